// Round 1
// baseline (546.120 us; speedup 1.0000x reference)
//
#include <hip/hip_runtime.h>

#define NEG 0.2f
#define BNEPS 1e-5f

// ---------------- GEMM1: h1 = x @ W1^T  [N,128], + s_src1/s_dst1 [N,4] ----------------
__global__ __launch_bounds__(256) void gemm1_kernel(
    const float* __restrict__ x, const float* __restrict__ W1,
    const float* __restrict__ asrc, const float* __restrict__ adst,
    float* __restrict__ h1, float* __restrict__ ssrc1, float* __restrict__ sdst1, int n)
{
    __shared__ float Wt[128][129];   // transposed, +1 pad: conflict-free write & read
    int tid = threadIdx.x;
    for (int idx = tid; idx < 128 * 128; idx += 256) {
        int j = idx >> 7, k = idx & 127;
        Wt[k][j] = W1[idx];
    }
    __syncthreads();
    int wave = tid >> 6, lane = tid & 63;
    int rbase = blockIdx.x * 64 + wave * 16;
    for (int it = 0; it < 16; ++it) {
        int r = rbase + it;
        if (r >= n) return;
        const float4* xr = (const float4*)(x + (size_t)r * 128);
        float a0 = 0.f, a1 = 0.f;
#pragma unroll
        for (int kk = 0; kk < 32; ++kk) {
            float4 xv = xr[kk];
            int k = kk * 4;
            a0 += xv.x * Wt[k + 0][lane];  a1 += xv.x * Wt[k + 0][lane + 64];
            a0 += xv.y * Wt[k + 1][lane];  a1 += xv.y * Wt[k + 1][lane + 64];
            a0 += xv.z * Wt[k + 2][lane];  a1 += xv.z * Wt[k + 2][lane + 64];
            a0 += xv.w * Wt[k + 3][lane];  a1 += xv.w * Wt[k + 3][lane + 64];
        }
        h1[(size_t)r * 128 + lane] = a0;
        h1[(size_t)r * 128 + 64 + lane] = a1;
        // attention scores: channel lane -> head lane>>5 (0/1); channel lane+64 -> head 2+(lane>>5)
        float ts0 = a0 * asrc[lane], ts1 = a1 * asrc[lane + 64];
        float td0 = a0 * adst[lane], td1 = a1 * adst[lane + 64];
#pragma unroll
        for (int m = 16; m >= 1; m >>= 1) {
            ts0 += __shfl_xor(ts0, m, 64); ts1 += __shfl_xor(ts1, m, 64);
            td0 += __shfl_xor(td0, m, 64); td1 += __shfl_xor(td1, m, 64);
        }
        if (lane == 0)  { ssrc1[r*4+0]=ts0; ssrc1[r*4+2]=ts1; sdst1[r*4+0]=td0; sdst1[r*4+2]=td1; }
        if (lane == 32) { ssrc1[r*4+1]=ts0; ssrc1[r*4+3]=ts1; sdst1[r*4+1]=td0; sdst1[r*4+3]=td1; }
    }
}

// ---------------- CSR build ----------------
__global__ void count_kernel(const int* __restrict__ dstp, int* __restrict__ deg, int E, int Etot)
{
    int i = blockIdx.x * blockDim.x + threadIdx.x;
    if (i >= Etot) return;
    int d = (i < E) ? dstp[i] : (i - E);
    atomicAdd(&deg[d], 1);
}

__global__ __launch_bounds__(1024) void scan_kernel(
    const int* __restrict__ deg, int* __restrict__ rowptr, int* __restrict__ cursor, int n)
{
    __shared__ int sums[1024];
    int tid = threadIdx.x;
    int chunk = (n + 1023) >> 10;
    int s0 = tid * chunk, s1 = min(s0 + chunk, n);
    int acc = 0;
    for (int i = s0; i < s1; ++i) acc += deg[i];
    sums[tid] = acc;
    __syncthreads();
    for (int off = 1; off < 1024; off <<= 1) {
        int v = 0;
        if (tid >= off) v = sums[tid - off];
        __syncthreads();
        sums[tid] += v;
        __syncthreads();
    }
    int base = (tid > 0) ? sums[tid - 1] : 0;
    for (int i = s0; i < s1; ++i) { rowptr[i] = base; cursor[i] = base; base += deg[i]; }
    if (tid == 0) rowptr[n] = sums[1023];
}

__global__ void scatter_kernel(const int* __restrict__ srcp, const int* __restrict__ dstp,
                               int* __restrict__ cursor, int* __restrict__ col, int E, int Etot)
{
    int i = blockIdx.x * blockDim.x + threadIdx.x;
    if (i >= Etot) return;
    int s, d;
    if (i < E) { s = srcp[i]; d = dstp[i]; } else { s = i - E; d = i - E; }
    int pos = atomicAdd(&cursor[d], 1);
    col[pos] = s;
}

// ---------------- GAT layer-1 aggregation + bias + BN1 + ELU ----------------
__global__ __launch_bounds__(256) void agg1_kernel(
    const float* __restrict__ h1, const float* __restrict__ ssrc1, const float* __restrict__ sdst1,
    const int* __restrict__ rowptr, const int* __restrict__ col,
    const float* __restrict__ b1, const float* __restrict__ g1, const float* __restrict__ be1,
    const float* __restrict__ mu1, const float* __restrict__ var1,
    float* __restrict__ hbn1, int n)
{
    int node = blockIdx.x * 4 + (threadIdx.x >> 6);
    int lane = threadIdx.x & 63;
    if (node >= n) return;
    int start = rowptr[node], end = rowptr[node + 1];
    float4 sdv = ((const float4*)sdst1)[node];
    // pass 1: segment max (4 heads)
    float m0 = -1e30f, m1 = -1e30f, m2 = -1e30f, m3 = -1e30f;
    for (int j = start + lane; j < end; j += 64) {
        int s = col[j];
        float4 sv = ((const float4*)ssrc1)[s];
        float e0 = sv.x + sdv.x; e0 = (e0 > 0.f) ? e0 : NEG * e0;
        float e1 = sv.y + sdv.y; e1 = (e1 > 0.f) ? e1 : NEG * e1;
        float e2 = sv.z + sdv.z; e2 = (e2 > 0.f) ? e2 : NEG * e2;
        float e3 = sv.w + sdv.w; e3 = (e3 > 0.f) ? e3 : NEG * e3;
        m0 = fmaxf(m0, e0); m1 = fmaxf(m1, e1); m2 = fmaxf(m2, e2); m3 = fmaxf(m3, e3);
    }
#pragma unroll
    for (int m = 32; m >= 1; m >>= 1) {
        m0 = fmaxf(m0, __shfl_xor(m0, m, 64)); m1 = fmaxf(m1, __shfl_xor(m1, m, 64));
        m2 = fmaxf(m2, __shfl_xor(m2, m, 64)); m3 = fmaxf(m3, __shfl_xor(m3, m, 64));
    }
    // pass 2: denom
    float d0 = 0.f, d1 = 0.f, d2 = 0.f, d3 = 0.f;
    for (int j = start + lane; j < end; j += 64) {
        int s = col[j];
        float4 sv = ((const float4*)ssrc1)[s];
        float e0 = sv.x + sdv.x; e0 = (e0 > 0.f) ? e0 : NEG * e0;
        float e1 = sv.y + sdv.y; e1 = (e1 > 0.f) ? e1 : NEG * e1;
        float e2 = sv.z + sdv.z; e2 = (e2 > 0.f) ? e2 : NEG * e2;
        float e3 = sv.w + sdv.w; e3 = (e3 > 0.f) ? e3 : NEG * e3;
        d0 += __expf(e0 - m0); d1 += __expf(e1 - m1);
        d2 += __expf(e2 - m2); d3 += __expf(e3 - m3);
    }
#pragma unroll
    for (int m = 32; m >= 1; m >>= 1) {
        d0 += __shfl_xor(d0, m, 64); d1 += __shfl_xor(d1, m, 64);
        d2 += __shfl_xor(d2, m, 64); d3 += __shfl_xor(d3, m, 64);
    }
    float iv0 = 1.f / d0, iv1 = 1.f / d1, iv2 = 1.f / d2, iv3 = 1.f / d3;
    // pass 3: weighted accumulate; lane owns channels (lane, lane+64)
    bool lo = lane < 32;
    float sdA = lo ? sdv.x : sdv.y, mA = lo ? m0 : m1, ivA = lo ? iv0 : iv1;
    float sdB = lo ? sdv.z : sdv.w, mB = lo ? m2 : m3, ivB = lo ? iv2 : iv3;
    float acc0 = 0.f, acc1 = 0.f;
    for (int j = start; j < end; ++j) {
        int s = col[j];
        float4 sv = ((const float4*)ssrc1)[s];
        float ea = (lo ? sv.x : sv.y) + sdA; ea = (ea > 0.f) ? ea : NEG * ea;
        float eb = (lo ? sv.z : sv.w) + sdB; eb = (eb > 0.f) ? eb : NEG * eb;
        float wa = __expf(ea - mA) * ivA;
        float wb = __expf(eb - mB) * ivB;
        acc0 += wa * h1[(size_t)s * 128 + lane];
        acc1 += wb * h1[(size_t)s * 128 + 64 + lane];
    }
    int c0 = lane, c1 = lane + 64;
    float v0 = acc0 + b1[c0];
    v0 = (v0 - mu1[c0]) * (g1[c0] * rsqrtf(var1[c0] + BNEPS)) + be1[c0];
    v0 = (v0 > 0.f) ? v0 : (__expf(v0) - 1.f);
    float v1 = acc1 + b1[c1];
    v1 = (v1 - mu1[c1]) * (g1[c1] * rsqrtf(var1[c1] + BNEPS)) + be1[c1];
    v1 = (v1 > 0.f) ? v1 : (__expf(v1) - 1.f);
    hbn1[(size_t)node * 128 + c0] = v0;
    hbn1[(size_t)node * 128 + c1] = v1;
}

// ---------------- GEMM2: h2 = hbn1 @ W2^T  [N,32], + s_src2/s_dst2 [N] ----------------
__global__ __launch_bounds__(256) void gemm2_kernel(
    const float* __restrict__ hbn1, const float* __restrict__ W2,
    const float* __restrict__ asrc2, const float* __restrict__ adst2,
    float* __restrict__ h2, float* __restrict__ ssrc2, float* __restrict__ sdst2, int n)
{
    __shared__ float Wt[128][33];
    int tid = threadIdx.x;
    for (int idx = tid; idx < 32 * 128; idx += 256) {
        int j = idx >> 7, k = idx & 127;
        Wt[k][j] = W2[idx];
    }
    __syncthreads();
    int wave = tid >> 6, lane = tid & 63, c = lane & 31, sub = lane >> 5;
    int base0 = blockIdx.x * 128 + wave * 32;
    for (int it = 0; it < 16; ++it) {
        int row = base0 + it * 2 + sub;
        if (row < n) {
            const float4* xr = (const float4*)(hbn1 + (size_t)row * 128);
            float acc = 0.f;
#pragma unroll
            for (int kk = 0; kk < 32; ++kk) {
                float4 xv = xr[kk];
                int k = kk * 4;
                acc += xv.x * Wt[k][c] + xv.y * Wt[k + 1][c] + xv.z * Wt[k + 2][c] + xv.w * Wt[k + 3][c];
            }
            h2[(size_t)row * 32 + c] = acc;
            float ts = acc * asrc2[c], td = acc * adst2[c];
#pragma unroll
            for (int m = 16; m >= 1; m >>= 1) { ts += __shfl_xor(ts, m, 64); td += __shfl_xor(td, m, 64); }
            if (c == 0) { ssrc2[row] = ts; sdst2[row] = td; }
        }
    }
}

// ---------------- GAT layer-2 aggregation + bias + BN2 + ELU + classifier ----------------
__global__ __launch_bounds__(256) void agg2_kernel(
    const float* __restrict__ h2, const float* __restrict__ ssrc2, const float* __restrict__ sdst2,
    const int* __restrict__ rowptr, const int* __restrict__ col,
    const float* __restrict__ b2, const float* __restrict__ g2, const float* __restrict__ be2,
    const float* __restrict__ mu2, const float* __restrict__ var2,
    const float* __restrict__ Wc, const float* __restrict__ bc,
    float* __restrict__ out, int n)
{
    int node = blockIdx.x * 4 + (threadIdx.x >> 6);
    int lane = threadIdx.x & 63;
    if (node >= n) return;
    int start = rowptr[node], end = rowptr[node + 1];
    float sd = sdst2[node];
    float mx = -1e30f;
    for (int j = start + lane; j < end; j += 64) {
        int s = col[j];
        float e = ssrc2[s] + sd; e = (e > 0.f) ? e : NEG * e;
        mx = fmaxf(mx, e);
    }
#pragma unroll
    for (int m = 32; m >= 1; m >>= 1) mx = fmaxf(mx, __shfl_xor(mx, m, 64));
    float dn = 0.f;
    for (int j = start + lane; j < end; j += 64) {
        int s = col[j];
        float e = ssrc2[s] + sd; e = (e > 0.f) ? e : NEG * e;
        dn += __expf(e - mx);
    }
#pragma unroll
    for (int m = 32; m >= 1; m >>= 1) dn += __shfl_xor(dn, m, 64);
    float iv = 1.f / dn;
    int c = lane & 31, sub = lane >> 5;
    float acc = 0.f;
    for (int j = start + sub; j < end; j += 2) {
        int s = col[j];
        float e = ssrc2[s] + sd; e = (e > 0.f) ? e : NEG * e;
        float w = __expf(e - mx) * iv;
        acc += w * h2[(size_t)s * 32 + c];
    }
    acc += __shfl_xor(acc, 32, 64);
    float v = acc + b2[c];
    v = (v - mu2[c]) * (g2[c] * rsqrtf(var2[c] + BNEPS)) + be2[c];
    v = (v > 0.f) ? v : (__expf(v) - 1.f);
#pragma unroll
    for (int o = 0; o < 10; ++o) {
        float t = v * Wc[o * 32 + c];
#pragma unroll
        for (int m = 16; m >= 1; m >>= 1) t += __shfl_xor(t, m, 64);
        if (lane == 0) out[(size_t)node * 10 + o] = t + bc[o];
    }
}

extern "C" void kernel_launch(void* const* d_in, const int* in_sizes, int n_in,
                              void* d_out, int out_size, void* d_ws, size_t ws_size,
                              hipStream_t stream)
{
    const float* x     = (const float*)d_in[0];
    const int*   ei    = (const int*)d_in[1];
    const float* W1    = (const float*)d_in[2];
    const float* asrc1 = (const float*)d_in[3];
    const float* adst1 = (const float*)d_in[4];
    const float* b1    = (const float*)d_in[5];
    const float* g1    = (const float*)d_in[6];
    const float* be1   = (const float*)d_in[7];
    const float* mu1   = (const float*)d_in[8];
    const float* var1  = (const float*)d_in[9];
    const float* W2    = (const float*)d_in[10];
    const float* asrc2 = (const float*)d_in[11];
    const float* adst2 = (const float*)d_in[12];
    const float* b2    = (const float*)d_in[13];
    const float* g2    = (const float*)d_in[14];
    const float* be2   = (const float*)d_in[15];
    const float* mu2   = (const float*)d_in[16];
    const float* var2  = (const float*)d_in[17];
    const float* Wc    = (const float*)d_in[18];
    const float* bc    = (const float*)d_in[19];

    int N_ = in_sizes[0] / 128;
    int E_ = in_sizes[1] / 2;
    int Etot = E_ + N_;
    const int* srcp = ei;
    const int* dstp = ei + E_;

    char* ws = (char*)d_ws;
    size_t off = 0;
    auto alloc = [&](size_t bytes) -> char* {
        char* p = ws + off;
        off += (bytes + 255) & ~(size_t)255;
        return p;
    };
    float* h1     = (float*)alloc((size_t)N_ * 128 * 4);
    float* hbn1   = (float*)alloc((size_t)N_ * 128 * 4);
    float* h2     = (float*)alloc((size_t)N_ * 32 * 4);
    float* ssrc1  = (float*)alloc((size_t)N_ * 4 * 4);
    float* sdst1  = (float*)alloc((size_t)N_ * 4 * 4);
    float* ssrc2  = (float*)alloc((size_t)N_ * 4);
    float* sdst2  = (float*)alloc((size_t)N_ * 4);
    int*   deg    = (int*)alloc((size_t)N_ * 4);
    int*   rowptr = (int*)alloc((size_t)(N_ + 1) * 4);
    int*   cursor = (int*)alloc((size_t)N_ * 4);
    int*   col    = (int*)alloc((size_t)Etot * 4);

    hipMemsetAsync(deg, 0, (size_t)N_ * 4, stream);
    gemm1_kernel<<<(N_ + 63) / 64, 256, 0, stream>>>(x, W1, asrc1, adst1, h1, ssrc1, sdst1, N_);
    count_kernel<<<(Etot + 255) / 256, 256, 0, stream>>>(dstp, deg, E_, Etot);
    scan_kernel<<<1, 1024, 0, stream>>>(deg, rowptr, cursor, N_);
    scatter_kernel<<<(Etot + 255) / 256, 256, 0, stream>>>(srcp, dstp, cursor, col, E_, Etot);
    agg1_kernel<<<(N_ + 3) / 4, 256, 0, stream>>>(h1, ssrc1, sdst1, rowptr, col,
                                                  b1, g1, be1, mu1, var1, hbn1, N_);
    gemm2_kernel<<<(N_ + 127) / 128, 256, 0, stream>>>(hbn1, W2, asrc2, adst2, h2, ssrc2, sdst2, N_);
    agg2_kernel<<<(N_ + 3) / 4, 256, 0, stream>>>(h2, ssrc2, sdst2, rowptr, col,
                                                  b2, g2, be2, mu2, var2, Wc, bc, (float*)d_out, N_);
}

// Round 2
// 406.196 us; speedup vs baseline: 1.3445x; 1.3445x over previous
//
#include <hip/hip_runtime.h>
#include <hip/hip_fp16.h>

#define NEG 0.2f
#define BNEPS 1e-5f

// ---------------- GEMM1: h1 = x @ W1^T  [N,128] (fp16 pairs) + s_src1/s_dst1 [N,4] ----------------
// lane owns channels (2*lane, 2*lane+1); head of c0 = lane>>4.
__global__ __launch_bounds__(256) void gemm1_kernel(
    const float* __restrict__ x, const float* __restrict__ W1,
    const float* __restrict__ asrc, const float* __restrict__ adst,
    __half2* __restrict__ h1h, float* __restrict__ ssrc1, float* __restrict__ sdst1, int n)
{
    __shared__ float Wlds[128 * 129];   // [c][k], row stride 129 (pad): 2-way bank alias only
    int tid = threadIdx.x;
    for (int idx = tid; idx < 128 * 128; idx += 256) {
        int c = idx >> 7, k = idx & 127;
        Wlds[c * 129 + k] = W1[idx];
    }
    __syncthreads();
    int wave = tid >> 6, lane = tid & 63;
    int c0 = 2 * lane, c1 = c0 + 1;
    float as0 = asrc[c0], as1 = asrc[c1], ad0 = adst[c0], ad1 = adst[c1];
    const float* w0p = &Wlds[c0 * 129];
    const float* w1p = &Wlds[c1 * 129];
    int rbase = blockIdx.x * 64 + wave * 16;
    for (int g = 0; g < 4; ++g) {
        int r = rbase + g * 4;
        if (r >= n) return;
        int nr = min(4, n - r);
        float2 acc[4] = {{0.f,0.f},{0.f,0.f},{0.f,0.f},{0.f,0.f}};
        const float4* xr0 = (const float4*)(x + (size_t)r * 128);
#pragma unroll 8
        for (int kk = 0; kk < 32; ++kk) {
            float4 xv[4];
#pragma unroll
            for (int q = 0; q < 4; ++q)
                if (q < nr) xv[q] = xr0[q * 32 + kk];
#pragma unroll
            for (int d = 0; d < 4; ++d) {
                int k = kk * 4 + d;
                float w0 = w0p[k], w1 = w1p[k];
#pragma unroll
                for (int q = 0; q < 4; ++q) {
                    const float* xf = (const float*)&xv[q];
                    acc[q].x += xf[d] * w0;
                    acc[q].y += xf[d] * w1;
                }
            }
        }
#pragma unroll
        for (int q = 0; q < 4; ++q) {
            if (q >= nr) break;
            int row = r + q;
            h1h[(size_t)row * 64 + lane] = __floats2half2_rn(acc[q].x, acc[q].y);
            float ts = acc[q].x * as0 + acc[q].y * as1;
            float td = acc[q].x * ad0 + acc[q].y * ad1;
#pragma unroll
            for (int m = 8; m >= 1; m >>= 1) {
                ts += __shfl_xor(ts, m, 64);
                td += __shfl_xor(td, m, 64);
            }
            if ((lane & 15) == 0) {
                ssrc1[row * 4 + (lane >> 4)] = ts;
                sdst1[row * 4 + (lane >> 4)] = td;
            }
        }
    }
}

// ---------------- CSR build ----------------
__global__ void count_kernel(const int* __restrict__ dstp, int* __restrict__ deg, int E, int Etot)
{
    int i = blockIdx.x * blockDim.x + threadIdx.x;
    if (i >= Etot) return;
    int d = (i < E) ? dstp[i] : (i - E);
    atomicAdd(&deg[d], 1);
}

__global__ __launch_bounds__(1024) void scan_kernel(
    const int* __restrict__ deg, int* __restrict__ rowptr, int* __restrict__ cursor, int n)
{
    __shared__ int sums[1024];
    int tid = threadIdx.x;
    int chunk = (n + 1023) >> 10;
    int s0 = tid * chunk, s1 = min(s0 + chunk, n);
    int acc = 0;
    for (int i = s0; i < s1; ++i) acc += deg[i];
    sums[tid] = acc;
    __syncthreads();
    for (int off = 1; off < 1024; off <<= 1) {
        int v = 0;
        if (tid >= off) v = sums[tid - off];
        __syncthreads();
        sums[tid] += v;
        __syncthreads();
    }
    int base = (tid > 0) ? sums[tid - 1] : 0;
    for (int i = s0; i < s1; ++i) { rowptr[i] = base; cursor[i] = base; base += deg[i]; }
    if (tid == 0) rowptr[n] = sums[1023];
}

__global__ void scatter_kernel(const int* __restrict__ srcp, const int* __restrict__ dstp,
                               int* __restrict__ cursor, int* __restrict__ col, int E, int Etot)
{
    int i = blockIdx.x * blockDim.x + threadIdx.x;
    if (i >= Etot) return;
    int s, d;
    if (i < E) { s = srcp[i]; d = dstp[i]; } else { s = i - E; d = i - E; }
    int pos = atomicAdd(&cursor[d], 1);
    col[pos] = s;
}

// ---------------- GAT layer-1: single-pass aggregate + bias + BN1 + ELU ----------------
// out = (sum_s exp(e_s) * h1[s]) / (sum_s exp(e_s))  -- identical to max-subtracted softmax.
__global__ __launch_bounds__(256) void agg1_kernel(
    const __half2* __restrict__ h1h, const float* __restrict__ ssrc1, const float* __restrict__ sdst1,
    const int* __restrict__ rowptr, const int* __restrict__ col,
    const float* __restrict__ b1, const float* __restrict__ g1, const float* __restrict__ be1,
    const float* __restrict__ mu1, const float* __restrict__ var1,
    float* __restrict__ hbn1, int n)
{
    int node = blockIdx.x * 4 + (threadIdx.x >> 6);
    int lane = threadIdx.x & 63;
    if (node >= n) return;
    int start = rowptr[node], end = rowptr[node + 1];
    int head = lane >> 4;
    float sdh = sdst1[node * 4 + head];
    float accx = 0.f, accy = 0.f, dn = 0.f;
#pragma unroll 4
    for (int j = start; j < end; ++j) {
        int s = col[j];
        float e = ssrc1[s * 4 + head] + sdh;
        e = (e > 0.f) ? e : NEG * e;
        float w = __expf(e);
        dn += w;
        float2 hf = __half22float2(h1h[(size_t)s * 64 + lane]);
        accx += w * hf.x;
        accy += w * hf.y;
    }
    float iv = 1.f / dn;
    float2 bv  = ((const float2*)b1)[lane];
    float2 gv  = ((const float2*)g1)[lane];
    float2 bev = ((const float2*)be1)[lane];
    float2 muv = ((const float2*)mu1)[lane];
    float2 vav = ((const float2*)var1)[lane];
    float v0 = accx * iv + bv.x;
    v0 = (v0 - muv.x) * (gv.x * rsqrtf(vav.x + BNEPS)) + bev.x;
    v0 = (v0 > 0.f) ? v0 : (__expf(v0) - 1.f);
    float v1 = accy * iv + bv.y;
    v1 = (v1 - muv.y) * (gv.y * rsqrtf(vav.y + BNEPS)) + bev.y;
    v1 = (v1 > 0.f) ? v1 : (__expf(v1) - 1.f);
    ((float2*)hbn1)[(size_t)node * 64 + lane] = make_float2(v0, v1);
}

// ---------------- GEMM2: h2 = hbn1 @ W2^T  [N,32] (fp16 pairs) + s_src2/s_dst2 [N] ----------------
// cp = lane&15 owns channels (2cp,2cp+1); sub = lane>>4 picks row within quad.
__global__ __launch_bounds__(256) void gemm2_kernel(
    const float* __restrict__ hbn1, const float* __restrict__ W2,
    const float* __restrict__ asrc2, const float* __restrict__ adst2,
    __half2* __restrict__ h2h, float* __restrict__ ssrc2, float* __restrict__ sdst2, int n)
{
    __shared__ float Wlds[32 * 129];
    int tid = threadIdx.x;
    for (int idx = tid; idx < 32 * 128; idx += 256) {
        int c = idx >> 7, k = idx & 127;
        Wlds[c * 129 + k] = W2[idx];
    }
    __syncthreads();
    int wave = tid >> 6, lane = tid & 63, cp = lane & 15, sub = lane >> 4;
    int c0 = 2 * cp, c1 = c0 + 1;
    float as0 = asrc2[c0], as1 = asrc2[c1], ad0 = adst2[c0], ad1 = adst2[c1];
    const float* w0p = &Wlds[c0 * 129];
    const float* w1p = &Wlds[c1 * 129];
    int rbase = blockIdx.x * 64 + wave * 16;
    for (int g = 0; g < 4; ++g) {
        int row = rbase + g * 4 + sub;
        if (row < n) {
            float ax = 0.f, ay = 0.f;
            const float4* xr = (const float4*)(hbn1 + (size_t)row * 128);
#pragma unroll 8
            for (int kk = 0; kk < 32; ++kk) {
                float4 xv = xr[kk];
                const float* xf = (const float*)&xv;
#pragma unroll
                for (int d = 0; d < 4; ++d) {
                    int k = kk * 4 + d;
                    ax += xf[d] * w0p[k];
                    ay += xf[d] * w1p[k];
                }
            }
            h2h[(size_t)row * 16 + cp] = __floats2half2_rn(ax, ay);
            float ts = ax * as0 + ay * as1;
            float td = ax * ad0 + ay * ad1;
#pragma unroll
            for (int m = 8; m >= 1; m >>= 1) {
                ts += __shfl_xor(ts, m, 64);
                td += __shfl_xor(td, m, 64);
            }
            if (cp == 0) { ssrc2[row] = ts; sdst2[row] = td; }
        }
    }
}

// ---------------- GAT layer-2: single-pass aggregate + BN2 + ELU + classifier ----------------
__global__ __launch_bounds__(256) void agg2_kernel(
    const __half2* __restrict__ h2h, const float* __restrict__ ssrc2, const float* __restrict__ sdst2,
    const int* __restrict__ rowptr, const int* __restrict__ col,
    const float* __restrict__ b2, const float* __restrict__ g2, const float* __restrict__ be2,
    const float* __restrict__ mu2, const float* __restrict__ var2,
    const float* __restrict__ Wc, const float* __restrict__ bc,
    float* __restrict__ out, int n)
{
    int node = blockIdx.x * 4 + (threadIdx.x >> 6);
    int lane = threadIdx.x & 63;
    if (node >= n) return;
    int start = rowptr[node], end = rowptr[node + 1];
    int cp = lane & 15, sub = lane >> 4;
    float sd = sdst2[node];
    float accx = 0.f, accy = 0.f, dn = 0.f;
    for (int j = start + sub; j < end; j += 4) {
        int s = col[j];
        float e = ssrc2[s] + sd;
        e = (e > 0.f) ? e : NEG * e;
        float w = __expf(e);
        dn += w;
        float2 hf = __half22float2(h2h[(size_t)s * 16 + cp]);
        accx += w * hf.x;
        accy += w * hf.y;
    }
    // combine the 4 sub-streams (bits 4,5 of lane)
    accx += __shfl_xor(accx, 16, 64); accx += __shfl_xor(accx, 32, 64);
    accy += __shfl_xor(accy, 16, 64); accy += __shfl_xor(accy, 32, 64);
    dn   += __shfl_xor(dn,   16, 64); dn   += __shfl_xor(dn,   32, 64);
    float iv = 1.f / dn;
    int c0 = 2 * cp, c1 = c0 + 1;
    float v0 = accx * iv + b2[c0];
    v0 = (v0 - mu2[c0]) * (g2[c0] * rsqrtf(var2[c0] + BNEPS)) + be2[c0];
    v0 = (v0 > 0.f) ? v0 : (__expf(v0) - 1.f);
    float v1 = accy * iv + b2[c1];
    v1 = (v1 - mu2[c1]) * (g2[c1] * rsqrtf(var2[c1] + BNEPS)) + be2[c1];
    v1 = (v1 > 0.f) ? v1 : (__expf(v1) - 1.f);
    // classifier: out[node, o] = sum_c v_c * Wc[o*32+c] + bc[o]; 4 outputs in parallel (one per sub)
#pragma unroll
    for (int rr = 0; rr < 3; ++rr) {
        int o = sub + rr * 4;
        float t = 0.f;
        if (o < 10) t = v0 * Wc[o * 32 + c0] + v1 * Wc[o * 32 + c1];
#pragma unroll
        for (int m = 8; m >= 1; m >>= 1) t += __shfl_xor(t, m, 64);
        if (cp == 0 && o < 10) out[(size_t)node * 10 + o] = t + bc[o];
    }
}

extern "C" void kernel_launch(void* const* d_in, const int* in_sizes, int n_in,
                              void* d_out, int out_size, void* d_ws, size_t ws_size,
                              hipStream_t stream)
{
    const float* x     = (const float*)d_in[0];
    const int*   ei    = (const int*)d_in[1];
    const float* W1    = (const float*)d_in[2];
    const float* asrc1 = (const float*)d_in[3];
    const float* adst1 = (const float*)d_in[4];
    const float* b1    = (const float*)d_in[5];
    const float* g1    = (const float*)d_in[6];
    const float* be1   = (const float*)d_in[7];
    const float* mu1   = (const float*)d_in[8];
    const float* var1  = (const float*)d_in[9];
    const float* W2    = (const float*)d_in[10];
    const float* asrc2 = (const float*)d_in[11];
    const float* adst2 = (const float*)d_in[12];
    const float* b2    = (const float*)d_in[13];
    const float* g2    = (const float*)d_in[14];
    const float* be2   = (const float*)d_in[15];
    const float* mu2   = (const float*)d_in[16];
    const float* var2  = (const float*)d_in[17];
    const float* Wc    = (const float*)d_in[18];
    const float* bc    = (const float*)d_in[19];

    int N_ = in_sizes[0] / 128;
    int E_ = in_sizes[1] / 2;
    int Etot = E_ + N_;
    const int* srcp = ei;
    const int* dstp = ei + E_;

    char* ws = (char*)d_ws;
    size_t off = 0;
    auto alloc = [&](size_t bytes) -> char* {
        char* p = ws + off;
        off += (bytes + 255) & ~(size_t)255;
        return p;
    };
    __half2* h1h   = (__half2*)alloc((size_t)N_ * 64 * 4);
    float*   hbn1  = (float*)alloc((size_t)N_ * 128 * 4);
    __half2* h2h   = (__half2*)alloc((size_t)N_ * 16 * 4);
    float*   ssrc1 = (float*)alloc((size_t)N_ * 4 * 4);
    float*   sdst1 = (float*)alloc((size_t)N_ * 4 * 4);
    float*   ssrc2 = (float*)alloc((size_t)N_ * 4);
    float*   sdst2 = (float*)alloc((size_t)N_ * 4);
    int*     deg   = (int*)alloc((size_t)N_ * 4);
    int*     rowptr= (int*)alloc((size_t)(N_ + 1) * 4);
    int*     cursor= (int*)alloc((size_t)N_ * 4);
    int*     col   = (int*)alloc((size_t)Etot * 4);

    hipMemsetAsync(deg, 0, (size_t)N_ * 4, stream);
    gemm1_kernel<<<(N_ + 63) / 64, 256, 0, stream>>>(x, W1, asrc1, adst1, h1h, ssrc1, sdst1, N_);
    count_kernel<<<(Etot + 255) / 256, 256, 0, stream>>>(dstp, deg, E_, Etot);
    scan_kernel<<<1, 1024, 0, stream>>>(deg, rowptr, cursor, N_);
    scatter_kernel<<<(Etot + 255) / 256, 256, 0, stream>>>(srcp, dstp, cursor, col, E_, Etot);
    agg1_kernel<<<(N_ + 3) / 4, 256, 0, stream>>>(h1h, ssrc1, sdst1, rowptr, col,
                                                  b1, g1, be1, mu1, var1, hbn1, N_);
    gemm2_kernel<<<(N_ + 63) / 64, 256, 0, stream>>>(hbn1, W2, asrc2, adst2, h2h, ssrc2, sdst2, N_);
    agg2_kernel<<<(N_ + 3) / 4, 256, 0, stream>>>(h2h, ssrc2, sdst2, rowptr, col,
                                                  b2, g2, be2, mu2, var2, Wc, bc, (float*)d_out, N_);
}

// Round 3
// 391.243 us; speedup vs baseline: 1.3959x; 1.0382x over previous
//
#include <hip/hip_runtime.h>
#include <hip/hip_fp16.h>

#define NEG 0.2f
#define BNEPS 1e-5f

// ---------------- GEMM1: h1 = x @ W1^T  [N,128] (fp16 pairs) + s_src1/s_dst1 [N,4] ----------------
// LDS holds W1 transposed [k][c] (pad 130). Lane owns channels (2*lane, 2*lane+1).
// Each wave computes 32 rows; accumulators in registers.
__global__ __launch_bounds__(256) void gemm1_kernel(
    const float* __restrict__ x, const float* __restrict__ W1,
    const float* __restrict__ asrc, const float* __restrict__ adst,
    __half2* __restrict__ h1h, float* __restrict__ ssrc1, float* __restrict__ sdst1, int n)
{
    __shared__ float Wt[128 * 130];   // [k][c], stride 130
    int tid = threadIdx.x;
    for (int idx = tid; idx < 128 * 128; idx += 256) {
        int c = idx >> 7, k = idx & 127;
        Wt[k * 130 + c] = W1[idx];    // coalesced global read
    }
    __syncthreads();
    int wave = tid >> 6, lane = tid & 63;
    int c0 = 2 * lane, c1 = c0 + 1;
    int rbase = blockIdx.x * 128 + wave * 32;
    int nr = n - rbase;               // valid rows for this wave (may be <=0)
    if (nr <= 0) return;
    float as0 = asrc[c0], as1 = asrc[c1], ad0 = adst[c0], ad1 = adst[c1];
    const float* xbase = x + (size_t)rbase * 128;

    float2 acc[32];
#pragma unroll
    for (int r = 0; r < 32; ++r) acc[r] = make_float2(0.f, 0.f);

    if (nr >= 32) {
        for (int kk = 0; kk < 32; ++kk) {
            float2 w[4];
#pragma unroll
            for (int d = 0; d < 4; ++d)
                w[d] = *(const float2*)&Wt[(4 * kk + d) * 130 + c0];
#pragma unroll
            for (int r = 0; r < 32; ++r) {
                float4 xv = *(const float4*)(xbase + r * 128 + kk * 4);
                acc[r].x += xv.x * w[0].x + xv.y * w[1].x + xv.z * w[2].x + xv.w * w[3].x;
                acc[r].y += xv.x * w[0].y + xv.y * w[1].y + xv.z * w[2].y + xv.w * w[3].y;
            }
        }
    } else {
        for (int kk = 0; kk < 32; ++kk) {
            float2 w[4];
#pragma unroll
            for (int d = 0; d < 4; ++d)
                w[d] = *(const float2*)&Wt[(4 * kk + d) * 130 + c0];
#pragma unroll
            for (int r = 0; r < 32; ++r) {
                if (r < nr) {
                    float4 xv = *(const float4*)(xbase + r * 128 + kk * 4);
                    acc[r].x += xv.x * w[0].x + xv.y * w[1].x + xv.z * w[2].x + xv.w * w[3].x;
                    acc[r].y += xv.x * w[0].y + xv.y * w[1].y + xv.z * w[2].y + xv.w * w[3].y;
                }
            }
        }
    }
#pragma unroll
    for (int r = 0; r < 32; ++r) {
        if (r >= nr) break;
        int row = rbase + r;
        h1h[(size_t)row * 64 + lane] = __floats2half2_rn(acc[r].x, acc[r].y);
        float ts = acc[r].x * as0 + acc[r].y * as1;
        float td = acc[r].x * ad0 + acc[r].y * ad1;
#pragma unroll
        for (int m = 8; m >= 1; m >>= 1) {
            ts += __shfl_xor(ts, m, 64);
            td += __shfl_xor(td, m, 64);
        }
        if ((lane & 15) == 0) {
            ssrc1[row * 4 + (lane >> 4)] = ts;
            sdst1[row * 4 + (lane >> 4)] = td;
        }
    }
}

// ---------------- CSR build ----------------
__global__ void count_kernel(const int* __restrict__ dstp, int* __restrict__ deg, int E, int Etot)
{
    int i = blockIdx.x * blockDim.x + threadIdx.x;
    if (i >= Etot) return;
    int d = (i < E) ? dstp[i] : (i - E);
    atomicAdd(&deg[d], 1);
}

// scan1: per-block exclusive scan of deg; writes exclusive prefix (pre) + block total (bsum)
__global__ __launch_bounds__(256) void scan1_kernel(
    const int* __restrict__ deg, int* __restrict__ pre, int* __restrict__ bsum, int n)
{
    int i = blockIdx.x * 256 + threadIdx.x;
    int lane = threadIdx.x & 63, wv = threadIdx.x >> 6;
    int v = (i < n) ? deg[i] : 0;
    int s = v;
#pragma unroll
    for (int m = 1; m < 64; m <<= 1) {
        int t = __shfl_up(s, m, 64);
        if (lane >= m) s += t;
    }
    __shared__ int wsum[4];
    if (lane == 63) wsum[wv] = s;
    __syncthreads();
    int add = 0;
    for (int w = 0; w < wv; ++w) add += wsum[w];
    s += add;
    if (i < n) pre[i] = s - v;               // exclusive within block
    if (threadIdx.x == 255) bsum[blockIdx.x] = s;   // block total (inclusive of padding zeros)
}

// scan2: single-wave inclusive scan of block sums (in place)
__global__ __launch_bounds__(64) void scan2_kernel(int* __restrict__ bsum, int nb)
{
    int lane = threadIdx.x;
    int carry = 0;
    for (int base = 0; base < nb; base += 64) {
        int i = base + lane;
        int v = (i < nb) ? bsum[i] : 0;
        int s = v;
#pragma unroll
        for (int m = 1; m < 64; m <<= 1) {
            int t = __shfl_up(s, m, 64);
            if (lane >= m) s += t;
        }
        if (i < nb) bsum[i] = s + carry;
        carry += __shfl(s, 63, 64);
    }
}

// scan3: rowptr[i] = pre[i] + blockoffset; cursor copy; rowptr[n] = Etot
__global__ void scan3_kernel(const int* __restrict__ pre, const int* __restrict__ bsum,
                             int* __restrict__ rowptr, int* __restrict__ cursor, int n, int etot)
{
    int i = blockIdx.x * 256 + threadIdx.x;
    if (i > n) return;
    if (i == n) { rowptr[n] = etot; return; }
    int off = (blockIdx.x > 0) ? bsum[blockIdx.x - 1] : 0;
    int v = pre[i] + off;
    rowptr[i] = v;
    cursor[i] = v;
}

__global__ void scatter_kernel(const int* __restrict__ srcp, const int* __restrict__ dstp,
                               int* __restrict__ cursor, int* __restrict__ col, int E, int Etot)
{
    int i = blockIdx.x * blockDim.x + threadIdx.x;
    if (i >= Etot) return;
    int s, d;
    if (i < E) { s = srcp[i]; d = dstp[i]; } else { s = i - E; d = i - E; }
    int pos = atomicAdd(&cursor[d], 1);
    col[pos] = s;
}

// ---------------- GAT layer-1: single-pass aggregate + bias + BN1 + ELU ----------------
__global__ __launch_bounds__(256) void agg1_kernel(
    const __half2* __restrict__ h1h, const float* __restrict__ ssrc1, const float* __restrict__ sdst1,
    const int* __restrict__ rowptr, const int* __restrict__ col,
    const float* __restrict__ b1, const float* __restrict__ g1, const float* __restrict__ be1,
    const float* __restrict__ mu1, const float* __restrict__ var1,
    float* __restrict__ hbn1, int n)
{
    int node = blockIdx.x * 4 + (threadIdx.x >> 6);
    int lane = threadIdx.x & 63;
    if (node >= n) return;
    int start = rowptr[node], end = rowptr[node + 1];
    int head = lane >> 4;
    float sdh = sdst1[node * 4 + head];
    float accx = 0.f, accy = 0.f, dn = 0.f;
#pragma unroll 4
    for (int j = start; j < end; ++j) {
        int s = col[j];
        float e = ssrc1[s * 4 + head] + sdh;
        e = (e > 0.f) ? e : NEG * e;
        float w = __expf(e);
        dn += w;
        float2 hf = __half22float2(h1h[(size_t)s * 64 + lane]);
        accx += w * hf.x;
        accy += w * hf.y;
    }
    float iv = 1.f / dn;
    float2 bv  = ((const float2*)b1)[lane];
    float2 gv  = ((const float2*)g1)[lane];
    float2 bev = ((const float2*)be1)[lane];
    float2 muv = ((const float2*)mu1)[lane];
    float2 vav = ((const float2*)var1)[lane];
    float v0 = accx * iv + bv.x;
    v0 = (v0 - muv.x) * (gv.x * rsqrtf(vav.x + BNEPS)) + bev.x;
    v0 = (v0 > 0.f) ? v0 : (__expf(v0) - 1.f);
    float v1 = accy * iv + bv.y;
    v1 = (v1 - muv.y) * (gv.y * rsqrtf(vav.y + BNEPS)) + bev.y;
    v1 = (v1 > 0.f) ? v1 : (__expf(v1) - 1.f);
    ((float2*)hbn1)[(size_t)node * 64 + lane] = make_float2(v0, v1);
}

// ---------------- GEMM2: h2 = hbn1 @ W2^T  [N,32] (fp16 pairs) + s_src2/s_dst2 [N] ----------------
// LDS W2 [k][c] (stride 34). cp=lane&15 owns channels (2cp,2cp+1); sub=lane>>4 picks row stream.
__global__ __launch_bounds__(256) void gemm2_kernel(
    const float* __restrict__ hbn1, const float* __restrict__ W2,
    const float* __restrict__ asrc2, const float* __restrict__ adst2,
    __half2* __restrict__ h2h, float* __restrict__ ssrc2, float* __restrict__ sdst2, int n)
{
    __shared__ float Wt[128 * 34];
    int tid = threadIdx.x;
    for (int idx = tid; idx < 32 * 128; idx += 256) {
        int c = idx >> 7, k = idx & 127;
        Wt[k * 34 + c] = W2[idx];
    }
    __syncthreads();
    int wave = tid >> 6, lane = tid & 63, cp = lane & 15, sub = lane >> 4;
    int c0 = 2 * cp, c1 = c0 + 1;
    int rbase = blockIdx.x * 128 + wave * 32;
    if (rbase >= n) return;
    float as0 = asrc2[c0], as1 = asrc2[c1], ad0 = adst2[c0], ad1 = adst2[c1];

    float2 acc[8];
#pragma unroll
    for (int r = 0; r < 8; ++r) acc[r] = make_float2(0.f, 0.f);

    bool full = (rbase + 32 <= n);
    for (int kk = 0; kk < 32; ++kk) {
        float2 w[4];
#pragma unroll
        for (int d = 0; d < 4; ++d)
            w[d] = *(const float2*)&Wt[(4 * kk + d) * 34 + c0];
#pragma unroll
        for (int r = 0; r < 8; ++r) {
            int row = rbase + r * 4 + sub;
            if (full || row < n) {
                float4 xv = *(const float4*)(hbn1 + (size_t)row * 128 + kk * 4);
                acc[r].x += xv.x * w[0].x + xv.y * w[1].x + xv.z * w[2].x + xv.w * w[3].x;
                acc[r].y += xv.x * w[0].y + xv.y * w[1].y + xv.z * w[2].y + xv.w * w[3].y;
            }
        }
    }
#pragma unroll
    for (int r = 0; r < 8; ++r) {
        int row = rbase + r * 4 + sub;
        if (row >= n) continue;
        h2h[(size_t)row * 16 + cp] = __floats2half2_rn(acc[r].x, acc[r].y);
        float ts = acc[r].x * as0 + acc[r].y * as1;
        float td = acc[r].x * ad0 + acc[r].y * ad1;
#pragma unroll
        for (int m = 8; m >= 1; m >>= 1) {
            ts += __shfl_xor(ts, m, 64);
            td += __shfl_xor(td, m, 64);
        }
        if (cp == 0) { ssrc2[row] = ts; sdst2[row] = td; }
    }
}

// ---------------- GAT layer-2: single-pass aggregate + BN2 + ELU + classifier ----------------
__global__ __launch_bounds__(256) void agg2_kernel(
    const __half2* __restrict__ h2h, const float* __restrict__ ssrc2, const float* __restrict__ sdst2,
    const int* __restrict__ rowptr, const int* __restrict__ col,
    const float* __restrict__ b2, const float* __restrict__ g2, const float* __restrict__ be2,
    const float* __restrict__ mu2, const float* __restrict__ var2,
    const float* __restrict__ Wc, const float* __restrict__ bc,
    float* __restrict__ out, int n)
{
    int node = blockIdx.x * 4 + (threadIdx.x >> 6);
    int lane = threadIdx.x & 63;
    if (node >= n) return;
    int start = rowptr[node], end = rowptr[node + 1];
    int cp = lane & 15, sub = lane >> 4;
    float sd = sdst2[node];
    float accx = 0.f, accy = 0.f, dn = 0.f;
    for (int j = start + sub; j < end; j += 4) {
        int s = col[j];
        float e = ssrc2[s] + sd;
        e = (e > 0.f) ? e : NEG * e;
        float w = __expf(e);
        dn += w;
        float2 hf = __half22float2(h2h[(size_t)s * 16 + cp]);
        accx += w * hf.x;
        accy += w * hf.y;
    }
    accx += __shfl_xor(accx, 16, 64); accx += __shfl_xor(accx, 32, 64);
    accy += __shfl_xor(accy, 16, 64); accy += __shfl_xor(accy, 32, 64);
    dn   += __shfl_xor(dn,   16, 64); dn   += __shfl_xor(dn,   32, 64);
    float iv = 1.f / dn;
    int c0 = 2 * cp, c1 = c0 + 1;
    float v0 = accx * iv + b2[c0];
    v0 = (v0 - mu2[c0]) * (g2[c0] * rsqrtf(var2[c0] + BNEPS)) + be2[c0];
    v0 = (v0 > 0.f) ? v0 : (__expf(v0) - 1.f);
    float v1 = accy * iv + b2[c1];
    v1 = (v1 - mu2[c1]) * (g2[c1] * rsqrtf(var2[c1] + BNEPS)) + be2[c1];
    v1 = (v1 > 0.f) ? v1 : (__expf(v1) - 1.f);
#pragma unroll
    for (int rr = 0; rr < 3; ++rr) {
        int o = sub + rr * 4;
        float t = 0.f;
        if (o < 10) t = v0 * Wc[o * 32 + c0] + v1 * Wc[o * 32 + c1];
#pragma unroll
        for (int m = 8; m >= 1; m >>= 1) t += __shfl_xor(t, m, 64);
        if (cp == 0 && o < 10) out[(size_t)node * 10 + o] = t + bc[o];
    }
}

extern "C" void kernel_launch(void* const* d_in, const int* in_sizes, int n_in,
                              void* d_out, int out_size, void* d_ws, size_t ws_size,
                              hipStream_t stream)
{
    const float* x     = (const float*)d_in[0];
    const int*   ei    = (const int*)d_in[1];
    const float* W1    = (const float*)d_in[2];
    const float* asrc1 = (const float*)d_in[3];
    const float* adst1 = (const float*)d_in[4];
    const float* b1    = (const float*)d_in[5];
    const float* g1    = (const float*)d_in[6];
    const float* be1   = (const float*)d_in[7];
    const float* mu1   = (const float*)d_in[8];
    const float* var1  = (const float*)d_in[9];
    const float* W2    = (const float*)d_in[10];
    const float* asrc2 = (const float*)d_in[11];
    const float* adst2 = (const float*)d_in[12];
    const float* b2    = (const float*)d_in[13];
    const float* g2    = (const float*)d_in[14];
    const float* be2   = (const float*)d_in[15];
    const float* mu2   = (const float*)d_in[16];
    const float* var2  = (const float*)d_in[17];
    const float* Wc    = (const float*)d_in[18];
    const float* bc    = (const float*)d_in[19];

    int N_ = in_sizes[0] / 128;
    int E_ = in_sizes[1] / 2;
    int Etot = E_ + N_;
    const int* srcp = ei;
    const int* dstp = ei + E_;

    char* ws = (char*)d_ws;
    size_t off = 0;
    auto alloc = [&](size_t bytes) -> char* {
        char* p = ws + off;
        off += (bytes + 255) & ~(size_t)255;
        return p;
    };
    __half2* h1h   = (__half2*)alloc((size_t)N_ * 64 * 4);
    float*   hbn1  = (float*)alloc((size_t)N_ * 128 * 4);
    __half2* h2h   = (__half2*)alloc((size_t)N_ * 16 * 4);
    float*   ssrc1 = (float*)alloc((size_t)N_ * 4 * 4);
    float*   sdst1 = (float*)alloc((size_t)N_ * 4 * 4);
    float*   ssrc2 = (float*)alloc((size_t)N_ * 4);
    float*   sdst2 = (float*)alloc((size_t)N_ * 4);
    int*     deg   = (int*)alloc((size_t)N_ * 4);
    int*     pre   = (int*)alloc((size_t)N_ * 4);
    int*     rowptr= (int*)alloc((size_t)(N_ + 1) * 4);
    int*     cursor= (int*)alloc((size_t)N_ * 4);
    int*     col   = (int*)alloc((size_t)Etot * 4);
    int nb = (N_ + 255) / 256;
    int*     bsum  = (int*)alloc((size_t)nb * 4);

    hipMemsetAsync(deg, 0, (size_t)N_ * 4, stream);
    gemm1_kernel<<<(N_ + 127) / 128, 256, 0, stream>>>(x, W1, asrc1, adst1, h1h, ssrc1, sdst1, N_);
    count_kernel<<<(Etot + 255) / 256, 256, 0, stream>>>(dstp, deg, E_, Etot);
    scan1_kernel<<<nb, 256, 0, stream>>>(deg, pre, bsum, N_);
    scan2_kernel<<<1, 64, 0, stream>>>(bsum, nb);
    scan3_kernel<<<(N_ + 256) / 256, 256, 0, stream>>>(pre, bsum, rowptr, cursor, N_, Etot);
    scatter_kernel<<<(Etot + 255) / 256, 256, 0, stream>>>(srcp, dstp, cursor, col, E_, Etot);
    agg1_kernel<<<(N_ + 3) / 4, 256, 0, stream>>>(h1h, ssrc1, sdst1, rowptr, col,
                                                  b1, g1, be1, mu1, var1, hbn1, N_);
    gemm2_kernel<<<(N_ + 127) / 128, 256, 0, stream>>>(hbn1, W2, asrc2, adst2, h2h, ssrc2, sdst2, N_);
    agg2_kernel<<<(N_ + 3) / 4, 256, 0, stream>>>(h2h, ssrc2, sdst2, rowptr, col,
                                                  b2, g2, be2, mu2, var2, Wc, bc, (float*)d_out, N_);
}

// Round 4
// 234.096 us; speedup vs baseline: 2.3329x; 1.6713x over previous
//
#include <hip/hip_runtime.h>
#include <hip/hip_fp16.h>

#define NEG 0.2f
#define BNEPS 1e-5f

// ---------------- GEMM1: h1 = x @ W1^T  [N,128] (fp16 pairs) + s_src1/s_dst1 [N,4] ----------------
// Tiled: block = 64 rows x 128 cols. Thread (tx=tid&15, ty=tid>>4) owns rows 4ty..4ty+3,
// cols {4tx..4tx+3} and {64+4tx..64+4tx+3}. A-tile k-major stride 68, B-tile k-major stride 132.
__global__ __launch_bounds__(256) void gemm1_kernel(
    const float* __restrict__ x, const float* __restrict__ W1,
    const float* __restrict__ asrc, const float* __restrict__ adst,
    __half2* __restrict__ h1h, float* __restrict__ ssrc1, float* __restrict__ sdst1, int n)
{
    __shared__ float At[32 * 68];    // [k][row]
    __shared__ float Bt[32 * 132];   // [k][col]
    int tid = threadIdx.x;
    int tx = tid & 15, ty = tid >> 4;
    int rbase = blockIdx.x * 64;

    int arow = tid >> 2, aq = tid & 3;       // A staging: row 0..63, quarter 0..3 (8 k each)
    int bc = tid >> 1, bq = tid & 1;         // B staging: col 0..127, half 0..1 (16 k each)
    int grow = rbase + arow;
    bool aval = grow < n;
    const float* xrow = x + (size_t)grow * 128;
    const float* wrow = W1 + (size_t)bc * 128;

    float acc_lo[4][4] = {{0.f}};
    float acc_hi[4][4] = {{0.f}};

    for (int kb = 0; kb < 128; kb += 32) {
        float4 av0, av1;
        if (aval) {
            av0 = *(const float4*)(xrow + kb + aq * 8);
            av1 = *(const float4*)(xrow + kb + aq * 8 + 4);
        } else {
            av0 = make_float4(0.f, 0.f, 0.f, 0.f); av1 = av0;
        }
        float4 bv0 = *(const float4*)(wrow + kb + bq * 16);
        float4 bv1 = *(const float4*)(wrow + kb + bq * 16 + 4);
        float4 bv2 = *(const float4*)(wrow + kb + bq * 16 + 8);
        float4 bv3 = *(const float4*)(wrow + kb + bq * 16 + 12);
        __syncthreads();   // previous iteration's reads done
        {
            const float* a0 = (const float*)&av0;
            const float* a1 = (const float*)&av1;
#pragma unroll
            for (int j = 0; j < 4; ++j) At[(aq * 8 + j) * 68 + arow] = a0[j];
#pragma unroll
            for (int j = 0; j < 4; ++j) At[(aq * 8 + 4 + j) * 68 + arow] = a1[j];
            const float* bp0 = (const float*)&bv0;
            const float* bp1 = (const float*)&bv1;
            const float* bp2 = (const float*)&bv2;
            const float* bp3 = (const float*)&bv3;
#pragma unroll
            for (int j = 0; j < 4; ++j) Bt[(bq * 16 + j) * 132 + bc] = bp0[j];
#pragma unroll
            for (int j = 0; j < 4; ++j) Bt[(bq * 16 + 4 + j) * 132 + bc] = bp1[j];
#pragma unroll
            for (int j = 0; j < 4; ++j) Bt[(bq * 16 + 8 + j) * 132 + bc] = bp2[j];
#pragma unroll
            for (int j = 0; j < 4; ++j) Bt[(bq * 16 + 12 + j) * 132 + bc] = bp3[j];
        }
        __syncthreads();
#pragma unroll
        for (int k = 0; k < 32; ++k) {
            float4 af = *(const float4*)&At[k * 68 + ty * 4];
            float4 bl = *(const float4*)&Bt[k * 132 + tx * 4];
            float4 bh = *(const float4*)&Bt[k * 132 + 64 + tx * 4];
            const float* ap = (const float*)&af;
            const float* blp = (const float*)&bl;
            const float* bhp = (const float*)&bh;
#pragma unroll
            for (int r = 0; r < 4; ++r) {
#pragma unroll
                for (int j = 0; j < 4; ++j) {
                    acc_lo[r][j] += ap[r] * blp[j];
                    acc_hi[r][j] += ap[r] * bhp[j];
                }
            }
        }
    }

    float4 as_lo = *(const float4*)(asrc + 4 * tx);
    float4 as_hi = *(const float4*)(asrc + 64 + 4 * tx);
    float4 ad_lo = *(const float4*)(adst + 4 * tx);
    float4 ad_hi = *(const float4*)(adst + 64 + 4 * tx);
    const float* aslp = (const float*)&as_lo;
    const float* ashp = (const float*)&as_hi;
    const float* adlp = (const float*)&ad_lo;
    const float* adhp = (const float*)&ad_hi;

#pragma unroll
    for (int r = 0; r < 4; ++r) {
        int row = rbase + 4 * ty + r;
        if (row >= n) continue;
        __half2* hp = h1h + (size_t)row * 64;
        hp[2 * tx]     = __floats2half2_rn(acc_lo[r][0], acc_lo[r][1]);
        hp[2 * tx + 1] = __floats2half2_rn(acc_lo[r][2], acc_lo[r][3]);
        hp[32 + 2 * tx]     = __floats2half2_rn(acc_hi[r][0], acc_hi[r][1]);
        hp[32 + 2 * tx + 1] = __floats2half2_rn(acc_hi[r][2], acc_hi[r][3]);
        float sls = 0.f, sld = 0.f, shs = 0.f, shd = 0.f;
#pragma unroll
        for (int j = 0; j < 4; ++j) {
            sls += acc_lo[r][j] * aslp[j];
            sld += acc_lo[r][j] * adlp[j];
            shs += acc_hi[r][j] * ashp[j];
            shd += acc_hi[r][j] * adhp[j];
        }
#pragma unroll
        for (int m = 1; m <= 4; m <<= 1) {
            sls += __shfl_xor(sls, m, 64);
            sld += __shfl_xor(sld, m, 64);
            shs += __shfl_xor(shs, m, 64);
            shd += __shfl_xor(shd, m, 64);
        }
        if ((tx & 7) == 0) {
            int hl = tx >> 3;          // head 0/1
            ssrc1[row * 4 + hl] = sls;
            sdst1[row * 4 + hl] = sld;
            ssrc1[row * 4 + 2 + hl] = shs;
            sdst1[row * 4 + 2 + hl] = shd;
        }
    }
}

// ---------------- CSR build ----------------
__global__ void count_kernel(const int* __restrict__ dstp, int* __restrict__ deg, int E, int Etot)
{
    int i = blockIdx.x * blockDim.x + threadIdx.x;
    if (i >= Etot) return;
    int d = (i < E) ? dstp[i] : (i - E);
    atomicAdd(&deg[d], 1);
}

__global__ __launch_bounds__(256) void scan1_kernel(
    const int* __restrict__ deg, int* __restrict__ pre, int* __restrict__ bsum, int n)
{
    int i = blockIdx.x * 256 + threadIdx.x;
    int lane = threadIdx.x & 63, wv = threadIdx.x >> 6;
    int v = (i < n) ? deg[i] : 0;
    int s = v;
#pragma unroll
    for (int m = 1; m < 64; m <<= 1) {
        int t = __shfl_up(s, m, 64);
        if (lane >= m) s += t;
    }
    __shared__ int wsum[4];
    if (lane == 63) wsum[wv] = s;
    __syncthreads();
    int add = 0;
    for (int w = 0; w < wv; ++w) add += wsum[w];
    s += add;
    if (i < n) pre[i] = s - v;
    if (threadIdx.x == 255) bsum[blockIdx.x] = s;
}

__global__ __launch_bounds__(64) void scan2_kernel(int* __restrict__ bsum, int nb)
{
    int lane = threadIdx.x;
    int carry = 0;
    for (int base = 0; base < nb; base += 64) {
        int i = base + lane;
        int v = (i < nb) ? bsum[i] : 0;
        int s = v;
#pragma unroll
        for (int m = 1; m < 64; m <<= 1) {
            int t = __shfl_up(s, m, 64);
            if (lane >= m) s += t;
        }
        if (i < nb) bsum[i] = s + carry;
        carry += __shfl(s, 63, 64);
    }
}

__global__ void scan3_kernel(const int* __restrict__ pre, const int* __restrict__ bsum,
                             int* __restrict__ rowptr, int* __restrict__ cursor, int n, int etot)
{
    int i = blockIdx.x * 256 + threadIdx.x;
    if (i > n) return;
    if (i == n) { rowptr[n] = etot; return; }
    int off = (blockIdx.x > 0) ? bsum[blockIdx.x - 1] : 0;
    int v = pre[i] + off;
    rowptr[i] = v;
    cursor[i] = v;
}

__global__ void scatter_kernel(const int* __restrict__ srcp, const int* __restrict__ dstp,
                               int* __restrict__ cursor, int* __restrict__ col, int E, int Etot)
{
    int i = blockIdx.x * blockDim.x + threadIdx.x;
    if (i >= Etot) return;
    int s, d;
    if (i < E) { s = srcp[i]; d = dstp[i]; } else { s = i - E; d = i - E; }
    int pos = atomicAdd(&cursor[d], 1);
    col[pos] = s;
}

// ---------------- GAT layer-1: single-pass aggregate + bias + BN1 + ELU ----------------
__global__ __launch_bounds__(256) void agg1_kernel(
    const __half2* __restrict__ h1h, const float* __restrict__ ssrc1, const float* __restrict__ sdst1,
    const int* __restrict__ rowptr, const int* __restrict__ col,
    const float* __restrict__ b1, const float* __restrict__ g1, const float* __restrict__ be1,
    const float* __restrict__ mu1, const float* __restrict__ var1,
    float* __restrict__ hbn1, int n)
{
    int node = blockIdx.x * 4 + (threadIdx.x >> 6);
    int lane = threadIdx.x & 63;
    if (node >= n) return;
    int start = rowptr[node], end = rowptr[node + 1];
    int head = lane >> 4;
    float sdh = sdst1[node * 4 + head];
    float accx = 0.f, accy = 0.f, dn = 0.f;
#pragma unroll 4
    for (int j = start; j < end; ++j) {
        int s = col[j];
        float e = ssrc1[s * 4 + head] + sdh;
        e = (e > 0.f) ? e : NEG * e;
        float w = __expf(e);
        dn += w;
        float2 hf = __half22float2(h1h[(size_t)s * 64 + lane]);
        accx += w * hf.x;
        accy += w * hf.y;
    }
    float iv = 1.f / dn;
    float2 bv  = ((const float2*)b1)[lane];
    float2 gv  = ((const float2*)g1)[lane];
    float2 bev = ((const float2*)be1)[lane];
    float2 muv = ((const float2*)mu1)[lane];
    float2 vav = ((const float2*)var1)[lane];
    float v0 = accx * iv + bv.x;
    v0 = (v0 - muv.x) * (gv.x * rsqrtf(vav.x + BNEPS)) + bev.x;
    v0 = (v0 > 0.f) ? v0 : (__expf(v0) - 1.f);
    float v1 = accy * iv + bv.y;
    v1 = (v1 - muv.y) * (gv.y * rsqrtf(vav.y + BNEPS)) + bev.y;
    v1 = (v1 > 0.f) ? v1 : (__expf(v1) - 1.f);
    ((float2*)hbn1)[(size_t)node * 64 + lane] = make_float2(v0, v1);
}

// ---------------- GEMM2: h2 = hbn1 @ W2^T  [N,32] (fp16 pairs) + s_src2/s_dst2 [N] ----------------
// Tiled: 64 rows x 32 cols. Thread owns rows 4ty..4ty+3, cols (2tx, 2tx+1).
__global__ __launch_bounds__(256) void gemm2_kernel(
    const float* __restrict__ hbn1, const float* __restrict__ W2,
    const float* __restrict__ asrc2, const float* __restrict__ adst2,
    __half2* __restrict__ h2h, float* __restrict__ ssrc2, float* __restrict__ sdst2, int n)
{
    __shared__ float At[32 * 68];   // [k][row]
    __shared__ float Bt[32 * 36];   // [k][col]
    int tid = threadIdx.x;
    int tx = tid & 15, ty = tid >> 4;
    int rbase = blockIdx.x * 64;

    int arow = tid >> 2, aq = tid & 3;
    int bc = tid >> 3, bq = tid & 7;        // col 0..31, eighth 0..7 (4 k each)
    int grow = rbase + arow;
    bool aval = grow < n;
    const float* xrow = hbn1 + (size_t)grow * 128;
    const float* wrow = W2 + (size_t)bc * 128;

    float acc[4][2] = {{0.f}};

    for (int kb = 0; kb < 128; kb += 32) {
        float4 av0, av1;
        if (aval) {
            av0 = *(const float4*)(xrow + kb + aq * 8);
            av1 = *(const float4*)(xrow + kb + aq * 8 + 4);
        } else {
            av0 = make_float4(0.f, 0.f, 0.f, 0.f); av1 = av0;
        }
        float4 bv = *(const float4*)(wrow + kb + bq * 4);
        __syncthreads();
        {
            const float* a0 = (const float*)&av0;
            const float* a1 = (const float*)&av1;
#pragma unroll
            for (int j = 0; j < 4; ++j) At[(aq * 8 + j) * 68 + arow] = a0[j];
#pragma unroll
            for (int j = 0; j < 4; ++j) At[(aq * 8 + 4 + j) * 68 + arow] = a1[j];
            const float* bp = (const float*)&bv;
#pragma unroll
            for (int j = 0; j < 4; ++j) Bt[(bq * 4 + j) * 36 + bc] = bp[j];
        }
        __syncthreads();
#pragma unroll
        for (int k = 0; k < 32; ++k) {
            float4 af = *(const float4*)&At[k * 68 + ty * 4];
            float2 bf = *(const float2*)&Bt[k * 36 + 2 * tx];
            const float* ap = (const float*)&af;
#pragma unroll
            for (int r = 0; r < 4; ++r) {
                acc[r][0] += ap[r] * bf.x;
                acc[r][1] += ap[r] * bf.y;
            }
        }
    }

    float as0 = asrc2[2 * tx], as1 = asrc2[2 * tx + 1];
    float ad0 = adst2[2 * tx], ad1 = adst2[2 * tx + 1];
#pragma unroll
    for (int r = 0; r < 4; ++r) {
        int row = rbase + 4 * ty + r;
        if (row >= n) continue;
        h2h[(size_t)row * 16 + tx] = __floats2half2_rn(acc[r][0], acc[r][1]);
        float ts = acc[r][0] * as0 + acc[r][1] * as1;
        float td = acc[r][0] * ad0 + acc[r][1] * ad1;
#pragma unroll
        for (int m = 1; m <= 8; m <<= 1) {
            ts += __shfl_xor(ts, m, 64);
            td += __shfl_xor(td, m, 64);
        }
        if (tx == 0) { ssrc2[row] = ts; sdst2[row] = td; }
    }
}

// ---------------- GAT layer-2: single-pass aggregate + BN2 + ELU + classifier ----------------
__global__ __launch_bounds__(256) void agg2_kernel(
    const __half2* __restrict__ h2h, const float* __restrict__ ssrc2, const float* __restrict__ sdst2,
    const int* __restrict__ rowptr, const int* __restrict__ col,
    const float* __restrict__ b2, const float* __restrict__ g2, const float* __restrict__ be2,
    const float* __restrict__ mu2, const float* __restrict__ var2,
    const float* __restrict__ Wc, const float* __restrict__ bc,
    float* __restrict__ out, int n)
{
    int node = blockIdx.x * 4 + (threadIdx.x >> 6);
    int lane = threadIdx.x & 63;
    if (node >= n) return;
    int start = rowptr[node], end = rowptr[node + 1];
    int cp = lane & 15, sub = lane >> 4;
    float sd = sdst2[node];
    float accx = 0.f, accy = 0.f, dn = 0.f;
    for (int j = start + sub; j < end; j += 4) {
        int s = col[j];
        float e = ssrc2[s] + sd;
        e = (e > 0.f) ? e : NEG * e;
        float w = __expf(e);
        dn += w;
        float2 hf = __half22float2(h2h[(size_t)s * 16 + cp]);
        accx += w * hf.x;
        accy += w * hf.y;
    }
    accx += __shfl_xor(accx, 16, 64); accx += __shfl_xor(accx, 32, 64);
    accy += __shfl_xor(accy, 16, 64); accy += __shfl_xor(accy, 32, 64);
    dn   += __shfl_xor(dn,   16, 64); dn   += __shfl_xor(dn,   32, 64);
    float iv = 1.f / dn;
    int c0 = 2 * cp, c1 = c0 + 1;
    float v0 = accx * iv + b2[c0];
    v0 = (v0 - mu2[c0]) * (g2[c0] * rsqrtf(var2[c0] + BNEPS)) + be2[c0];
    v0 = (v0 > 0.f) ? v0 : (__expf(v0) - 1.f);
    float v1 = accy * iv + b2[c1];
    v1 = (v1 - mu2[c1]) * (g2[c1] * rsqrtf(var2[c1] + BNEPS)) + be2[c1];
    v1 = (v1 > 0.f) ? v1 : (__expf(v1) - 1.f);
#pragma unroll
    for (int rr = 0; rr < 3; ++rr) {
        int o = sub + rr * 4;
        float t = 0.f;
        if (o < 10) t = v0 * Wc[o * 32 + c0] + v1 * Wc[o * 32 + c1];
#pragma unroll
        for (int m = 8; m >= 1; m >>= 1) t += __shfl_xor(t, m, 64);
        if (cp == 0 && o < 10) out[(size_t)node * 10 + o] = t + bc[o];
    }
}

extern "C" void kernel_launch(void* const* d_in, const int* in_sizes, int n_in,
                              void* d_out, int out_size, void* d_ws, size_t ws_size,
                              hipStream_t stream)
{
    const float* x     = (const float*)d_in[0];
    const int*   ei    = (const int*)d_in[1];
    const float* W1    = (const float*)d_in[2];
    const float* asrc1 = (const float*)d_in[3];
    const float* adst1 = (const float*)d_in[4];
    const float* b1    = (const float*)d_in[5];
    const float* g1    = (const float*)d_in[6];
    const float* be1   = (const float*)d_in[7];
    const float* mu1   = (const float*)d_in[8];
    const float* var1  = (const float*)d_in[9];
    const float* W2    = (const float*)d_in[10];
    const float* asrc2 = (const float*)d_in[11];
    const float* adst2 = (const float*)d_in[12];
    const float* b2    = (const float*)d_in[13];
    const float* g2    = (const float*)d_in[14];
    const float* be2   = (const float*)d_in[15];
    const float* mu2   = (const float*)d_in[16];
    const float* var2  = (const float*)d_in[17];
    const float* Wc    = (const float*)d_in[18];
    const float* bc    = (const float*)d_in[19];

    int N_ = in_sizes[0] / 128;
    int E_ = in_sizes[1] / 2;
    int Etot = E_ + N_;
    const int* srcp = ei;
    const int* dstp = ei + E_;

    char* ws = (char*)d_ws;
    size_t off = 0;
    auto alloc = [&](size_t bytes) -> char* {
        char* p = ws + off;
        off += (bytes + 255) & ~(size_t)255;
        return p;
    };
    __half2* h1h   = (__half2*)alloc((size_t)N_ * 64 * 4);
    float*   hbn1  = (float*)alloc((size_t)N_ * 128 * 4);
    __half2* h2h   = (__half2*)alloc((size_t)N_ * 16 * 4);
    float*   ssrc1 = (float*)alloc((size_t)N_ * 4 * 4);
    float*   sdst1 = (float*)alloc((size_t)N_ * 4 * 4);
    float*   ssrc2 = (float*)alloc((size_t)N_ * 4);
    float*   sdst2 = (float*)alloc((size_t)N_ * 4);
    int*     deg   = (int*)alloc((size_t)N_ * 4);
    int*     pre   = (int*)alloc((size_t)N_ * 4);
    int*     rowptr= (int*)alloc((size_t)(N_ + 1) * 4);
    int*     cursor= (int*)alloc((size_t)N_ * 4);
    int*     col   = (int*)alloc((size_t)Etot * 4);
    int nb = (N_ + 255) / 256;
    int*     bsum  = (int*)alloc((size_t)nb * 4);

    hipMemsetAsync(deg, 0, (size_t)N_ * 4, stream);
    gemm1_kernel<<<(N_ + 63) / 64, 256, 0, stream>>>(x, W1, asrc1, adst1, h1h, ssrc1, sdst1, N_);
    count_kernel<<<(Etot + 255) / 256, 256, 0, stream>>>(dstp, deg, E_, Etot);
    scan1_kernel<<<nb, 256, 0, stream>>>(deg, pre, bsum, N_);
    scan2_kernel<<<1, 64, 0, stream>>>(bsum, nb);
    scan3_kernel<<<(N_ + 256) / 256, 256, 0, stream>>>(pre, bsum, rowptr, cursor, N_, Etot);
    scatter_kernel<<<(Etot + 255) / 256, 256, 0, stream>>>(srcp, dstp, cursor, col, E_, Etot);
    agg1_kernel<<<(N_ + 3) / 4, 256, 0, stream>>>(h1h, ssrc1, sdst1, rowptr, col,
                                                  b1, g1, be1, mu1, var1, hbn1, N_);
    gemm2_kernel<<<(N_ + 63) / 64, 256, 0, stream>>>(hbn1, W2, asrc2, adst2, h2h, ssrc2, sdst2, N_);
    agg2_kernel<<<(N_ + 3) / 4, 256, 0, stream>>>(h2h, ssrc2, sdst2, rowptr, col,
                                                  b2, g2, be2, mu2, var2, Wc, bc, (float*)d_out, N_);
}

// Round 5
// 220.261 us; speedup vs baseline: 2.4794x; 1.0628x over previous
//
#include <hip/hip_runtime.h>
#include <hip/hip_fp16.h>

#define NEG 0.2f
#define BNEPS 1e-5f
#define NPART 8
#define SUBR 8

// ---------------- GEMM1: h1 = x @ W1^T  [N,128] (fp16 pairs) + s_src1/s_dst1 [N,4] ----------------
__global__ __launch_bounds__(256) void gemm1_kernel(
    const float* __restrict__ x, const float* __restrict__ W1,
    const float* __restrict__ asrc, const float* __restrict__ adst,
    __half2* __restrict__ h1h, float* __restrict__ ssrc1, float* __restrict__ sdst1, int n)
{
    __shared__ float At[32 * 68];    // [k][row]
    __shared__ float Bt[32 * 132];   // [k][col]
    int tid = threadIdx.x;
    int tx = tid & 15, ty = tid >> 4;
    int rbase = blockIdx.x * 64;

    int arow = tid >> 2, aq = tid & 3;
    int bc = tid >> 1, bq = tid & 1;
    int grow = rbase + arow;
    bool aval = grow < n;
    const float* xrow = x + (size_t)grow * 128;
    const float* wrow = W1 + (size_t)bc * 128;

    float acc_lo[4][4] = {{0.f}};
    float acc_hi[4][4] = {{0.f}};

    for (int kb = 0; kb < 128; kb += 32) {
        float4 av0, av1;
        if (aval) {
            av0 = *(const float4*)(xrow + kb + aq * 8);
            av1 = *(const float4*)(xrow + kb + aq * 8 + 4);
        } else {
            av0 = make_float4(0.f, 0.f, 0.f, 0.f); av1 = av0;
        }
        float4 bv0 = *(const float4*)(wrow + kb + bq * 16);
        float4 bv1 = *(const float4*)(wrow + kb + bq * 16 + 4);
        float4 bv2 = *(const float4*)(wrow + kb + bq * 16 + 8);
        float4 bv3 = *(const float4*)(wrow + kb + bq * 16 + 12);
        __syncthreads();
        {
            const float* a0 = (const float*)&av0;
            const float* a1 = (const float*)&av1;
#pragma unroll
            for (int j = 0; j < 4; ++j) At[(aq * 8 + j) * 68 + arow] = a0[j];
#pragma unroll
            for (int j = 0; j < 4; ++j) At[(aq * 8 + 4 + j) * 68 + arow] = a1[j];
            const float* bp0 = (const float*)&bv0;
            const float* bp1 = (const float*)&bv1;
            const float* bp2 = (const float*)&bv2;
            const float* bp3 = (const float*)&bv3;
#pragma unroll
            for (int j = 0; j < 4; ++j) Bt[(bq * 16 + j) * 132 + bc] = bp0[j];
#pragma unroll
            for (int j = 0; j < 4; ++j) Bt[(bq * 16 + 4 + j) * 132 + bc] = bp1[j];
#pragma unroll
            for (int j = 0; j < 4; ++j) Bt[(bq * 16 + 8 + j) * 132 + bc] = bp2[j];
#pragma unroll
            for (int j = 0; j < 4; ++j) Bt[(bq * 16 + 12 + j) * 132 + bc] = bp3[j];
        }
        __syncthreads();
#pragma unroll
        for (int k = 0; k < 32; ++k) {
            float4 af = *(const float4*)&At[k * 68 + ty * 4];
            float4 bl = *(const float4*)&Bt[k * 132 + tx * 4];
            float4 bh = *(const float4*)&Bt[k * 132 + 64 + tx * 4];
            const float* ap = (const float*)&af;
            const float* blp = (const float*)&bl;
            const float* bhp = (const float*)&bh;
#pragma unroll
            for (int r = 0; r < 4; ++r) {
#pragma unroll
                for (int j = 0; j < 4; ++j) {
                    acc_lo[r][j] += ap[r] * blp[j];
                    acc_hi[r][j] += ap[r] * bhp[j];
                }
            }
        }
    }

    float4 as_lo = *(const float4*)(asrc + 4 * tx);
    float4 as_hi = *(const float4*)(asrc + 64 + 4 * tx);
    float4 ad_lo = *(const float4*)(adst + 4 * tx);
    float4 ad_hi = *(const float4*)(adst + 64 + 4 * tx);
    const float* aslp = (const float*)&as_lo;
    const float* ashp = (const float*)&as_hi;
    const float* adlp = (const float*)&ad_lo;
    const float* adhp = (const float*)&ad_hi;

#pragma unroll
    for (int r = 0; r < 4; ++r) {
        int row = rbase + 4 * ty + r;
        if (row >= n) continue;
        __half2* hp = h1h + (size_t)row * 64;
        hp[2 * tx]     = __floats2half2_rn(acc_lo[r][0], acc_lo[r][1]);
        hp[2 * tx + 1] = __floats2half2_rn(acc_lo[r][2], acc_lo[r][3]);
        hp[32 + 2 * tx]     = __floats2half2_rn(acc_hi[r][0], acc_hi[r][1]);
        hp[32 + 2 * tx + 1] = __floats2half2_rn(acc_hi[r][2], acc_hi[r][3]);
        float sls = 0.f, sld = 0.f, shs = 0.f, shd = 0.f;
#pragma unroll
        for (int j = 0; j < 4; ++j) {
            sls += acc_lo[r][j] * aslp[j];
            sld += acc_lo[r][j] * adlp[j];
            shs += acc_hi[r][j] * ashp[j];
            shd += acc_hi[r][j] * adhp[j];
        }
#pragma unroll
        for (int m = 1; m <= 4; m <<= 1) {
            sls += __shfl_xor(sls, m, 64);
            sld += __shfl_xor(sld, m, 64);
            shs += __shfl_xor(shs, m, 64);
            shd += __shfl_xor(shd, m, 64);
        }
        if ((tx & 7) == 0) {
            int hl = tx >> 3;
            ssrc1[row * 4 + hl] = sls;
            sdst1[row * 4 + hl] = sld;
            ssrc1[row * 4 + 2 + hl] = shs;
            sdst1[row * 4 + 2 + hl] = shd;
        }
    }
}

// ---------------- CSR build: pass 1 — partition edges into 8 dst-range buckets ----------------
// Block-local LDS binning: 1 global atomic per bucket per 2048-edge tile; 2 KB bursts.
__global__ __launch_bounds__(256) void part_kernel(
    const int* __restrict__ srcp, const int* __restrict__ dstp, int E, int Etot, int chunk,
    int2* __restrict__ pairs, int pcap, int* __restrict__ pcur)
{
    __shared__ int lcnt[NPART], lbase[NPART];
    const int PER = 8;                       // edges per thread
    int t0 = blockIdx.x * 256 * PER;
    int tid = threadIdx.x;
    if (tid < NPART) lcnt[tid] = 0;
    __syncthreads();
    int myd[PER], mys[PER], myp[PER];
#pragma unroll
    for (int j = 0; j < PER; ++j) {
        int i = t0 + j * 256 + tid;
        if (i < Etot) {
            int s, d;
            if (i < E) { s = srcp[i]; d = dstp[i]; } else { s = i - E; d = i - E; }
            myd[j] = d; mys[j] = s; myp[j] = d / chunk;
            atomicAdd(&lcnt[myp[j]], 1);
        } else myp[j] = -1;
    }
    __syncthreads();
    if (tid < NPART) {
        lbase[tid] = atomicAdd(&pcur[tid], lcnt[tid]);
        lcnt[tid] = 0;
    }
    __syncthreads();
#pragma unroll
    for (int j = 0; j < PER; ++j) {
        if (myp[j] >= 0) {
            int r = atomicAdd(&lcnt[myp[j]], 1);
            int pos = lbase[myp[j]] + r;
            if (pos < pcap) pairs[(size_t)myp[j] * pcap + pos] = make_int2(myd[j], mys[j]);
        }
    }
}

// ---------------- CSR build: pass 2 — per (partition, subrange) block: deg count, scan, scatter ----
// p = blockIdx&7 so each partition maps to one XCD (round-robin dispatch) -> col region L2-local.
__global__ __launch_bounds__(1024) void csr_kernel(
    const int2* __restrict__ pairs, int pcap, const int* __restrict__ pcnt,
    int* __restrict__ rowptr, int* __restrict__ col, int N, int chunk, int Etot)
{
    __shared__ int ldeg[1056];
    __shared__ int wtmp[16];
    int p = blockIdx.x & (NPART - 1);
    int s = blockIdx.x >> 3;
    int subchunk = (chunk + SUBR - 1) / SUBR;
    int plo = p * chunk;
    int phi = min(plo + chunk, N);
    int lo = plo + s * subchunk;
    int hi = min(lo + subchunk, phi);
    int len = max(hi - lo, 0);
    int tid = threadIdx.x;
    int lane = tid & 63, wv = tid >> 6;

    for (int i = tid; i < len; i += 1024) ldeg[i] = 0;
    __syncthreads();

    int cnt = min(pcnt[p], pcap);
    const int2* pp = pairs + (size_t)p * pcap;
    int below = 0;
    for (int i = tid; i < cnt; i += 1024) {
        int d = pp[i].x;
        if (d < lo) ++below;
        else if (d < hi) atomicAdd(&ldeg[d - lo], 1);
    }
    // block-reduce 'below'
#pragma unroll
    for (int m = 32; m >= 1; m >>= 1) below += __shfl_xor(below, m, 64);
    if (lane == 0) wtmp[wv] = below;
    __syncthreads();
    int below_tot = 0;
    for (int w = 0; w < 16; ++w) below_tot += wtmp[w];
    __syncthreads();

    // block scan of ldeg[0..len) (len <= 1024, one element per thread)
    int v = (tid < len) ? ldeg[tid] : 0;
    int inc = v;
#pragma unroll
    for (int m = 1; m < 64; m <<= 1) {
        int t = __shfl_up(inc, m, 64);
        if (lane >= m) inc += t;
    }
    if (lane == 63) wtmp[wv] = inc;
    __syncthreads();
    int woff = 0;
    for (int w = 0; w < wv; ++w) woff += wtmp[w];
    int excl = inc - v + woff;
    __syncthreads();

    int pbase = 0;
    for (int q = 0; q < p; ++q) pbase += pcnt[q];
    int base = pbase + below_tot;
    if (tid < len) {
        rowptr[lo + tid] = base + excl;
        ldeg[tid] = base + excl;       // becomes global cursor
    }
    if (hi == N && tid == 0) rowptr[N] = Etot;
    __syncthreads();

    // scatter col
    for (int i = tid; i < cnt; i += 1024) {
        int2 e = pp[i];
        int d = e.x;
        if (d >= lo && d < hi) {
            int pos = atomicAdd(&ldeg[d - lo], 1);
            col[pos] = e.y;
        }
    }
}

// ---------------- GAT layer-1: single-pass aggregate + bias + BN1 + ELU ----------------
__global__ __launch_bounds__(256) void agg1_kernel(
    const __half2* __restrict__ h1h, const float* __restrict__ ssrc1, const float* __restrict__ sdst1,
    const int* __restrict__ rowptr, const int* __restrict__ col,
    const float* __restrict__ b1, const float* __restrict__ g1, const float* __restrict__ be1,
    const float* __restrict__ mu1, const float* __restrict__ var1,
    float* __restrict__ hbn1, int n)
{
    int node = blockIdx.x * 4 + (threadIdx.x >> 6);
    int lane = threadIdx.x & 63;
    if (node >= n) return;
    int start = rowptr[node], end = rowptr[node + 1];
    int head = lane >> 4;
    float sdh = sdst1[node * 4 + head];
    float accx = 0.f, accy = 0.f, dn = 0.f;
#pragma unroll 4
    for (int j = start; j < end; ++j) {
        int s = col[j];
        float e = ssrc1[s * 4 + head] + sdh;
        e = (e > 0.f) ? e : NEG * e;
        float w = __expf(e);
        dn += w;
        float2 hf = __half22float2(h1h[(size_t)s * 64 + lane]);
        accx += w * hf.x;
        accy += w * hf.y;
    }
    float iv = 1.f / dn;
    float2 bv  = ((const float2*)b1)[lane];
    float2 gv  = ((const float2*)g1)[lane];
    float2 bev = ((const float2*)be1)[lane];
    float2 muv = ((const float2*)mu1)[lane];
    float2 vav = ((const float2*)var1)[lane];
    float v0 = accx * iv + bv.x;
    v0 = (v0 - muv.x) * (gv.x * rsqrtf(vav.x + BNEPS)) + bev.x;
    v0 = (v0 > 0.f) ? v0 : (__expf(v0) - 1.f);
    float v1 = accy * iv + bv.y;
    v1 = (v1 - muv.y) * (gv.y * rsqrtf(vav.y + BNEPS)) + bev.y;
    v1 = (v1 > 0.f) ? v1 : (__expf(v1) - 1.f);
    ((float2*)hbn1)[(size_t)node * 64 + lane] = make_float2(v0, v1);
}

// ---------------- GEMM2: h2 = hbn1 @ W2^T  [N,32] (fp16 pairs) + s_src2/s_dst2 [N] ----------------
__global__ __launch_bounds__(256) void gemm2_kernel(
    const float* __restrict__ hbn1, const float* __restrict__ W2,
    const float* __restrict__ asrc2, const float* __restrict__ adst2,
    __half2* __restrict__ h2h, float* __restrict__ ssrc2, float* __restrict__ sdst2, int n)
{
    __shared__ float At[32 * 68];
    __shared__ float Bt[32 * 36];
    int tid = threadIdx.x;
    int tx = tid & 15, ty = tid >> 4;
    int rbase = blockIdx.x * 64;

    int arow = tid >> 2, aq = tid & 3;
    int bc = tid >> 3, bq = tid & 7;
    int grow = rbase + arow;
    bool aval = grow < n;
    const float* xrow = hbn1 + (size_t)grow * 128;
    const float* wrow = W2 + (size_t)bc * 128;

    float acc[4][2] = {{0.f}};

    for (int kb = 0; kb < 128; kb += 32) {
        float4 av0, av1;
        if (aval) {
            av0 = *(const float4*)(xrow + kb + aq * 8);
            av1 = *(const float4*)(xrow + kb + aq * 8 + 4);
        } else {
            av0 = make_float4(0.f, 0.f, 0.f, 0.f); av1 = av0;
        }
        float4 bv = *(const float4*)(wrow + kb + bq * 4);
        __syncthreads();
        {
            const float* a0 = (const float*)&av0;
            const float* a1 = (const float*)&av1;
#pragma unroll
            for (int j = 0; j < 4; ++j) At[(aq * 8 + j) * 68 + arow] = a0[j];
#pragma unroll
            for (int j = 0; j < 4; ++j) At[(aq * 8 + 4 + j) * 68 + arow] = a1[j];
            const float* bp = (const float*)&bv;
#pragma unroll
            for (int j = 0; j < 4; ++j) Bt[(bq * 4 + j) * 36 + bc] = bp[j];
        }
        __syncthreads();
#pragma unroll
        for (int k = 0; k < 32; ++k) {
            float4 af = *(const float4*)&At[k * 68 + ty * 4];
            float2 bf = *(const float2*)&Bt[k * 36 + 2 * tx];
            const float* ap = (const float*)&af;
#pragma unroll
            for (int r = 0; r < 4; ++r) {
                acc[r][0] += ap[r] * bf.x;
                acc[r][1] += ap[r] * bf.y;
            }
        }
    }

    float as0 = asrc2[2 * tx], as1 = asrc2[2 * tx + 1];
    float ad0 = adst2[2 * tx], ad1 = adst2[2 * tx + 1];
#pragma unroll
    for (int r = 0; r < 4; ++r) {
        int row = rbase + 4 * ty + r;
        if (row >= n) continue;
        h2h[(size_t)row * 16 + tx] = __floats2half2_rn(acc[r][0], acc[r][1]);
        float ts = acc[r][0] * as0 + acc[r][1] * as1;
        float td = acc[r][0] * ad0 + acc[r][1] * ad1;
#pragma unroll
        for (int m = 1; m <= 8; m <<= 1) {
            ts += __shfl_xor(ts, m, 64);
            td += __shfl_xor(td, m, 64);
        }
        if (tx == 0) { ssrc2[row] = ts; sdst2[row] = td; }
    }
}

// ---------------- GAT layer-2: single-pass aggregate + BN2 + ELU + classifier ----------------
__global__ __launch_bounds__(256) void agg2_kernel(
    const __half2* __restrict__ h2h, const float* __restrict__ ssrc2, const float* __restrict__ sdst2,
    const int* __restrict__ rowptr, const int* __restrict__ col,
    const float* __restrict__ b2, const float* __restrict__ g2, const float* __restrict__ be2,
    const float* __restrict__ mu2, const float* __restrict__ var2,
    const float* __restrict__ Wc, const float* __restrict__ bc,
    float* __restrict__ out, int n)
{
    int node = blockIdx.x * 4 + (threadIdx.x >> 6);
    int lane = threadIdx.x & 63;
    if (node >= n) return;
    int start = rowptr[node], end = rowptr[node + 1];
    int cp = lane & 15, sub = lane >> 4;
    float sd = sdst2[node];
    float accx = 0.f, accy = 0.f, dn = 0.f;
    for (int j = start + sub; j < end; j += 4) {
        int s = col[j];
        float e = ssrc2[s] + sd;
        e = (e > 0.f) ? e : NEG * e;
        float w = __expf(e);
        dn += w;
        float2 hf = __half22float2(h2h[(size_t)s * 16 + cp]);
        accx += w * hf.x;
        accy += w * hf.y;
    }
    accx += __shfl_xor(accx, 16, 64); accx += __shfl_xor(accx, 32, 64);
    accy += __shfl_xor(accy, 16, 64); accy += __shfl_xor(accy, 32, 64);
    dn   += __shfl_xor(dn,   16, 64); dn   += __shfl_xor(dn,   32, 64);
    float iv = 1.f / dn;
    int c0 = 2 * cp, c1 = c0 + 1;
    float v0 = accx * iv + b2[c0];
    v0 = (v0 - mu2[c0]) * (g2[c0] * rsqrtf(var2[c0] + BNEPS)) + be2[c0];
    v0 = (v0 > 0.f) ? v0 : (__expf(v0) - 1.f);
    float v1 = accy * iv + b2[c1];
    v1 = (v1 - mu2[c1]) * (g2[c1] * rsqrtf(var2[c1] + BNEPS)) + be2[c1];
    v1 = (v1 > 0.f) ? v1 : (__expf(v1) - 1.f);
#pragma unroll
    for (int rr = 0; rr < 3; ++rr) {
        int o = sub + rr * 4;
        float t = 0.f;
        if (o < 10) t = v0 * Wc[o * 32 + c0] + v1 * Wc[o * 32 + c1];
#pragma unroll
        for (int m = 8; m >= 1; m >>= 1) t += __shfl_xor(t, m, 64);
        if (cp == 0 && o < 10) out[(size_t)node * 10 + o] = t + bc[o];
    }
}

extern "C" void kernel_launch(void* const* d_in, const int* in_sizes, int n_in,
                              void* d_out, int out_size, void* d_ws, size_t ws_size,
                              hipStream_t stream)
{
    const float* x     = (const float*)d_in[0];
    const int*   ei    = (const int*)d_in[1];
    const float* W1    = (const float*)d_in[2];
    const float* asrc1 = (const float*)d_in[3];
    const float* adst1 = (const float*)d_in[4];
    const float* b1    = (const float*)d_in[5];
    const float* g1    = (const float*)d_in[6];
    const float* be1   = (const float*)d_in[7];
    const float* mu1   = (const float*)d_in[8];
    const float* var1  = (const float*)d_in[9];
    const float* W2    = (const float*)d_in[10];
    const float* asrc2 = (const float*)d_in[11];
    const float* adst2 = (const float*)d_in[12];
    const float* b2    = (const float*)d_in[13];
    const float* g2    = (const float*)d_in[14];
    const float* be2   = (const float*)d_in[15];
    const float* mu2   = (const float*)d_in[16];
    const float* var2  = (const float*)d_in[17];
    const float* Wc    = (const float*)d_in[18];
    const float* bc    = (const float*)d_in[19];

    int N_ = in_sizes[0] / 128;
    int E_ = in_sizes[1] / 2;
    int Etot = E_ + N_;
    const int* srcp = ei;
    const int* dstp = ei + E_;
    int chunk = (N_ + NPART - 1) / NPART;
    int pcap = Etot / NPART + 4096;

    char* ws = (char*)d_ws;
    size_t off = 0;
    auto alloc = [&](size_t bytes) -> char* {
        char* p = ws + off;
        off += (bytes + 255) & ~(size_t)255;
        return p;
    };
    __half2* h1h   = (__half2*)alloc((size_t)N_ * 64 * 4);
    float*   hbn1  = (float*)alloc((size_t)N_ * 128 * 4);
    __half2* h2h   = (__half2*)alloc((size_t)N_ * 16 * 4);
    float*   ssrc1 = (float*)alloc((size_t)N_ * 4 * 4);
    float*   sdst1 = (float*)alloc((size_t)N_ * 4 * 4);
    float*   ssrc2 = (float*)alloc((size_t)N_ * 4);
    float*   sdst2 = (float*)alloc((size_t)N_ * 4);
    int*     rowptr= (int*)alloc((size_t)(N_ + 1) * 4);
    int*     col   = (int*)alloc((size_t)Etot * 4);
    int2*    pairs = (int2*)alloc((size_t)NPART * pcap * 8);
    int*     pcur  = (int*)alloc((size_t)NPART * 4);

    hipMemsetAsync(pcur, 0, NPART * 4, stream);
    gemm1_kernel<<<(N_ + 63) / 64, 256, 0, stream>>>(x, W1, asrc1, adst1, h1h, ssrc1, sdst1, N_);
    int per_block = 256 * 8;
    part_kernel<<<(Etot + per_block - 1) / per_block, 256, 0, stream>>>(
        srcp, dstp, E_, Etot, chunk, pairs, pcap, pcur);
    csr_kernel<<<NPART * SUBR, 1024, 0, stream>>>(pairs, pcap, pcur, rowptr, col, N_, chunk, Etot);
    agg1_kernel<<<(N_ + 3) / 4, 256, 0, stream>>>(h1h, ssrc1, sdst1, rowptr, col,
                                                  b1, g1, be1, mu1, var1, hbn1, N_);
    gemm2_kernel<<<(N_ + 63) / 64, 256, 0, stream>>>(hbn1, W2, asrc2, adst2, h2h, ssrc2, sdst2, N_);
    agg2_kernel<<<(N_ + 3) / 4, 256, 0, stream>>>(h2h, ssrc2, sdst2, rowptr, col,
                                                  b2, g2, be2, mu2, var2, Wc, bc, (float*)d_out, N_);
}

// Round 6
// 167.051 us; speedup vs baseline: 3.2692x; 1.3185x over previous
//
#include <hip/hip_runtime.h>
#include <hip/hip_fp16.h>

#define NEG 0.2f
#define BNEPS 1e-5f
#define NPART 256

// ---------------- GEMM1: h1 = x @ W1^T  [N,128] (fp16 pairs) + s_src1/s_dst1 [N,4] ----------------
__global__ __launch_bounds__(256) void gemm1_kernel(
    const float* __restrict__ x, const float* __restrict__ W1,
    const float* __restrict__ asrc, const float* __restrict__ adst,
    __half2* __restrict__ h1h, float* __restrict__ ssrc1, float* __restrict__ sdst1, int n)
{
    __shared__ float At[32 * 68];    // [k][row]
    __shared__ float Bt[32 * 132];   // [k][col]
    int tid = threadIdx.x;
    int tx = tid & 15, ty = tid >> 4;
    int rbase = blockIdx.x * 64;

    int arow = tid >> 2, aq = tid & 3;
    int bc = tid >> 1, bq = tid & 1;
    int grow = rbase + arow;
    bool aval = grow < n;
    const float* xrow = x + (size_t)grow * 128;
    const float* wrow = W1 + (size_t)bc * 128;

    float acc_lo[4][4] = {{0.f}};
    float acc_hi[4][4] = {{0.f}};

    for (int kb = 0; kb < 128; kb += 32) {
        float4 av0, av1;
        if (aval) {
            av0 = *(const float4*)(xrow + kb + aq * 8);
            av1 = *(const float4*)(xrow + kb + aq * 8 + 4);
        } else {
            av0 = make_float4(0.f, 0.f, 0.f, 0.f); av1 = av0;
        }
        float4 bv0 = *(const float4*)(wrow + kb + bq * 16);
        float4 bv1 = *(const float4*)(wrow + kb + bq * 16 + 4);
        float4 bv2 = *(const float4*)(wrow + kb + bq * 16 + 8);
        float4 bv3 = *(const float4*)(wrow + kb + bq * 16 + 12);
        __syncthreads();
        {
            const float* a0 = (const float*)&av0;
            const float* a1 = (const float*)&av1;
#pragma unroll
            for (int j = 0; j < 4; ++j) At[(aq * 8 + j) * 68 + arow] = a0[j];
#pragma unroll
            for (int j = 0; j < 4; ++j) At[(aq * 8 + 4 + j) * 68 + arow] = a1[j];
            const float* bp0 = (const float*)&bv0;
            const float* bp1 = (const float*)&bv1;
            const float* bp2 = (const float*)&bv2;
            const float* bp3 = (const float*)&bv3;
#pragma unroll
            for (int j = 0; j < 4; ++j) Bt[(bq * 16 + j) * 132 + bc] = bp0[j];
#pragma unroll
            for (int j = 0; j < 4; ++j) Bt[(bq * 16 + 4 + j) * 132 + bc] = bp1[j];
#pragma unroll
            for (int j = 0; j < 4; ++j) Bt[(bq * 16 + 8 + j) * 132 + bc] = bp2[j];
#pragma unroll
            for (int j = 0; j < 4; ++j) Bt[(bq * 16 + 12 + j) * 132 + bc] = bp3[j];
        }
        __syncthreads();
#pragma unroll
        for (int k = 0; k < 32; ++k) {
            float4 af = *(const float4*)&At[k * 68 + ty * 4];
            float4 bl = *(const float4*)&Bt[k * 132 + tx * 4];
            float4 bh = *(const float4*)&Bt[k * 132 + 64 + tx * 4];
            const float* ap = (const float*)&af;
            const float* blp = (const float*)&bl;
            const float* bhp = (const float*)&bh;
#pragma unroll
            for (int r = 0; r < 4; ++r) {
#pragma unroll
                for (int j = 0; j < 4; ++j) {
                    acc_lo[r][j] += ap[r] * blp[j];
                    acc_hi[r][j] += ap[r] * bhp[j];
                }
            }
        }
    }

    float4 as_lo = *(const float4*)(asrc + 4 * tx);
    float4 as_hi = *(const float4*)(asrc + 64 + 4 * tx);
    float4 ad_lo = *(const float4*)(adst + 4 * tx);
    float4 ad_hi = *(const float4*)(adst + 64 + 4 * tx);
    const float* aslp = (const float*)&as_lo;
    const float* ashp = (const float*)&as_hi;
    const float* adlp = (const float*)&ad_lo;
    const float* adhp = (const float*)&ad_hi;

#pragma unroll
    for (int r = 0; r < 4; ++r) {
        int row = rbase + 4 * ty + r;
        if (row >= n) continue;
        __half2* hp = h1h + (size_t)row * 64;
        hp[2 * tx]     = __floats2half2_rn(acc_lo[r][0], acc_lo[r][1]);
        hp[2 * tx + 1] = __floats2half2_rn(acc_lo[r][2], acc_lo[r][3]);
        hp[32 + 2 * tx]     = __floats2half2_rn(acc_hi[r][0], acc_hi[r][1]);
        hp[32 + 2 * tx + 1] = __floats2half2_rn(acc_hi[r][2], acc_hi[r][3]);
        float sls = 0.f, sld = 0.f, shs = 0.f, shd = 0.f;
#pragma unroll
        for (int j = 0; j < 4; ++j) {
            sls += acc_lo[r][j] * aslp[j];
            sld += acc_lo[r][j] * adlp[j];
            shs += acc_hi[r][j] * ashp[j];
            shd += acc_hi[r][j] * adhp[j];
        }
#pragma unroll
        for (int m = 1; m <= 4; m <<= 1) {
            sls += __shfl_xor(sls, m, 64);
            sld += __shfl_xor(sld, m, 64);
            shs += __shfl_xor(shs, m, 64);
            shd += __shfl_xor(shd, m, 64);
        }
        if ((tx & 7) == 0) {
            int hl = tx >> 3;
            ssrc1[row * 4 + hl] = sls;
            sdst1[row * 4 + hl] = sld;
            ssrc1[row * 4 + 2 + hl] = shs;
            sdst1[row * 4 + 2 + hl] = shd;
        }
    }
}

// ---------------- CSR pass 1: partition edges into 256 dst-range buckets ----------------
__global__ __launch_bounds__(256) void part_kernel(
    const int* __restrict__ srcp, const int* __restrict__ dstp, int E, int Etot, int chunk,
    int2* __restrict__ pairs, int pcap, int* __restrict__ pcur)
{
    __shared__ int lcnt[NPART], lbase[NPART];
    const int PER = 8;
    int t0 = blockIdx.x * 256 * PER;
    int tid = threadIdx.x;
    lcnt[tid] = 0;
    __syncthreads();
    int myd[PER], mys[PER], myp[PER];
#pragma unroll
    for (int j = 0; j < PER; ++j) {
        int i = t0 + j * 256 + tid;
        if (i < Etot) {
            int s, d;
            if (i < E) { s = srcp[i]; d = dstp[i]; } else { s = i - E; d = i - E; }
            myd[j] = d; mys[j] = s; myp[j] = d / chunk;
            atomicAdd(&lcnt[myp[j]], 1);
        } else myp[j] = -1;
    }
    __syncthreads();
    lbase[tid] = atomicAdd(&pcur[tid], lcnt[tid]);
    lcnt[tid] = 0;
    __syncthreads();
#pragma unroll
    for (int j = 0; j < PER; ++j) {
        if (myp[j] >= 0) {
            int r = atomicAdd(&lcnt[myp[j]], 1);
            int pos = lbase[myp[j]] + r;
            if (pos < pcap) pairs[(size_t)myp[j] * pcap + pos] = make_int2(myd[j], mys[j]);
        }
    }
}

// ---------------- CSR pass 2: one block per partition — deg count, scan, scatter ----------------
__global__ __launch_bounds__(256) void csr_kernel(
    const int2* __restrict__ pairs, int pcap, const int* __restrict__ pcnt,
    int* __restrict__ rowptr, int* __restrict__ col, int N, int chunk, int Etot)
{
    __shared__ int ldeg[NPART];
    __shared__ int wtmp[4];
    __shared__ int sh_pbase;
    int p = blockIdx.x;
    int lo = p * chunk;
    int hi = min(lo + chunk, N);
    int len = max(hi - lo, 0);
    int tid = threadIdx.x;
    int lane = tid & 63, wv = tid >> 6;

    // global base for this partition: exclusive prefix of pcnt at index p
    {
        int v = pcnt[tid];
        int inc = v;
#pragma unroll
        for (int m = 1; m < 64; m <<= 1) {
            int t = __shfl_up(inc, m, 64);
            if (lane >= m) inc += t;
        }
        if (lane == 63) wtmp[wv] = inc;
        __syncthreads();
        int woff = 0;
        for (int w = 0; w < wv; ++w) woff += wtmp[w];
        if (tid == p) sh_pbase = inc - v + woff;
        ldeg[tid] = 0;
        __syncthreads();
    }

    int cnt = min(pcnt[p], pcap);
    const int2* pp = pairs + (size_t)p * pcap;
    for (int i = tid; i < cnt; i += 256) {
        atomicAdd(&ldeg[pp[i].x - lo], 1);
    }
    __syncthreads();

    // block scan of ldeg[0..len)
    int v = (tid < len) ? ldeg[tid] : 0;
    int inc = v;
#pragma unroll
    for (int m = 1; m < 64; m <<= 1) {
        int t = __shfl_up(inc, m, 64);
        if (lane >= m) inc += t;
    }
    if (lane == 63) wtmp[wv] = inc;
    __syncthreads();
    int woff = 0;
    for (int w = 0; w < wv; ++w) woff += wtmp[w];
    int excl = inc - v + woff;
    int base = sh_pbase;
    __syncthreads();
    if (tid < len) {
        rowptr[lo + tid] = base + excl;
        ldeg[tid] = base + excl;        // becomes global cursor
    }
    if (p == NPART - 1 && tid == 0) rowptr[N] = Etot;
    __syncthreads();

    // scatter col (pairs are L2-hot from the count pass)
    for (int i = tid; i < cnt; i += 256) {
        int2 e = pp[i];
        int pos = atomicAdd(&ldeg[e.x - lo], 1);
        col[pos] = e.y;
    }
}

// ---------------- GAT layer-1: single-pass aggregate + bias + BN1 + ELU ----------------
__global__ __launch_bounds__(256) void agg1_kernel(
    const __half2* __restrict__ h1h, const float* __restrict__ ssrc1, const float* __restrict__ sdst1,
    const int* __restrict__ rowptr, const int* __restrict__ col,
    const float* __restrict__ b1, const float* __restrict__ g1, const float* __restrict__ be1,
    const float* __restrict__ mu1, const float* __restrict__ var1,
    float* __restrict__ hbn1, int n)
{
    int node = blockIdx.x * 4 + (threadIdx.x >> 6);
    int lane = threadIdx.x & 63;
    if (node >= n) return;
    int start = rowptr[node], end = rowptr[node + 1];
    int head = lane >> 4;
    float sdh = sdst1[node * 4 + head];
    float accx = 0.f, accy = 0.f, dn = 0.f;
#pragma unroll 4
    for (int j = start; j < end; ++j) {
        int s = col[j];
        float e = ssrc1[s * 4 + head] + sdh;
        e = (e > 0.f) ? e : NEG * e;
        float w = __expf(e);
        dn += w;
        float2 hf = __half22float2(h1h[(size_t)s * 64 + lane]);
        accx += w * hf.x;
        accy += w * hf.y;
    }
    float iv = 1.f / dn;
    float2 bv  = ((const float2*)b1)[lane];
    float2 gv  = ((const float2*)g1)[lane];
    float2 bev = ((const float2*)be1)[lane];
    float2 muv = ((const float2*)mu1)[lane];
    float2 vav = ((const float2*)var1)[lane];
    float v0 = accx * iv + bv.x;
    v0 = (v0 - muv.x) * (gv.x * rsqrtf(vav.x + BNEPS)) + bev.x;
    v0 = (v0 > 0.f) ? v0 : (__expf(v0) - 1.f);
    float v1 = accy * iv + bv.y;
    v1 = (v1 - muv.y) * (gv.y * rsqrtf(vav.y + BNEPS)) + bev.y;
    v1 = (v1 > 0.f) ? v1 : (__expf(v1) - 1.f);
    ((float2*)hbn1)[(size_t)node * 64 + lane] = make_float2(v0, v1);
}

// ---------------- GEMM2: h2 = hbn1 @ W2^T  [N,32] (fp16 pairs) + s_src2/s_dst2 [N] ----------------
__global__ __launch_bounds__(256) void gemm2_kernel(
    const float* __restrict__ hbn1, const float* __restrict__ W2,
    const float* __restrict__ asrc2, const float* __restrict__ adst2,
    __half2* __restrict__ h2h, float* __restrict__ ssrc2, float* __restrict__ sdst2, int n)
{
    __shared__ float At[32 * 68];
    __shared__ float Bt[32 * 36];
    int tid = threadIdx.x;
    int tx = tid & 15, ty = tid >> 4;
    int rbase = blockIdx.x * 64;

    int arow = tid >> 2, aq = tid & 3;
    int bc = tid >> 3, bq = tid & 7;
    int grow = rbase + arow;
    bool aval = grow < n;
    const float* xrow = hbn1 + (size_t)grow * 128;
    const float* wrow = W2 + (size_t)bc * 128;

    float acc[4][2] = {{0.f}};

    for (int kb = 0; kb < 128; kb += 32) {
        float4 av0, av1;
        if (aval) {
            av0 = *(const float4*)(xrow + kb + aq * 8);
            av1 = *(const float4*)(xrow + kb + aq * 8 + 4);
        } else {
            av0 = make_float4(0.f, 0.f, 0.f, 0.f); av1 = av0;
        }
        float4 bv = *(const float4*)(wrow + kb + bq * 4);
        __syncthreads();
        {
            const float* a0 = (const float*)&av0;
            const float* a1 = (const float*)&av1;
#pragma unroll
            for (int j = 0; j < 4; ++j) At[(aq * 8 + j) * 68 + arow] = a0[j];
#pragma unroll
            for (int j = 0; j < 4; ++j) At[(aq * 8 + 4 + j) * 68 + arow] = a1[j];
            const float* bp = (const float*)&bv;
#pragma unroll
            for (int j = 0; j < 4; ++j) Bt[(bq * 4 + j) * 36 + bc] = bp[j];
        }
        __syncthreads();
#pragma unroll
        for (int k = 0; k < 32; ++k) {
            float4 af = *(const float4*)&At[k * 68 + ty * 4];
            float2 bf = *(const float2*)&Bt[k * 36 + 2 * tx];
            const float* ap = (const float*)&af;
#pragma unroll
            for (int r = 0; r < 4; ++r) {
                acc[r][0] += ap[r] * bf.x;
                acc[r][1] += ap[r] * bf.y;
            }
        }
    }

    float as0 = asrc2[2 * tx], as1 = asrc2[2 * tx + 1];
    float ad0 = adst2[2 * tx], ad1 = adst2[2 * tx + 1];
#pragma unroll
    for (int r = 0; r < 4; ++r) {
        int row = rbase + 4 * ty + r;
        if (row >= n) continue;
        h2h[(size_t)row * 16 + tx] = __floats2half2_rn(acc[r][0], acc[r][1]);
        float ts = acc[r][0] * as0 + acc[r][1] * as1;
        float td = acc[r][0] * ad0 + acc[r][1] * ad1;
#pragma unroll
        for (int m = 1; m <= 8; m <<= 1) {
            ts += __shfl_xor(ts, m, 64);
            td += __shfl_xor(td, m, 64);
        }
        if (tx == 0) { ssrc2[row] = ts; sdst2[row] = td; }
    }
}

// ---------------- GAT layer-2: single-pass aggregate + BN2 + ELU + classifier ----------------
__global__ __launch_bounds__(256) void agg2_kernel(
    const __half2* __restrict__ h2h, const float* __restrict__ ssrc2, const float* __restrict__ sdst2,
    const int* __restrict__ rowptr, const int* __restrict__ col,
    const float* __restrict__ b2, const float* __restrict__ g2, const float* __restrict__ be2,
    const float* __restrict__ mu2, const float* __restrict__ var2,
    const float* __restrict__ Wc, const float* __restrict__ bc,
    float* __restrict__ out, int n)
{
    int node = blockIdx.x * 4 + (threadIdx.x >> 6);
    int lane = threadIdx.x & 63;
    if (node >= n) return;
    int start = rowptr[node], end = rowptr[node + 1];
    int cp = lane & 15, sub = lane >> 4;
    float sd = sdst2[node];
    float accx = 0.f, accy = 0.f, dn = 0.f;
    for (int j = start + sub; j < end; j += 4) {
        int s = col[j];
        float e = ssrc2[s] + sd;
        e = (e > 0.f) ? e : NEG * e;
        float w = __expf(e);
        dn += w;
        float2 hf = __half22float2(h2h[(size_t)s * 16 + cp]);
        accx += w * hf.x;
        accy += w * hf.y;
    }
    accx += __shfl_xor(accx, 16, 64); accx += __shfl_xor(accx, 32, 64);
    accy += __shfl_xor(accy, 16, 64); accy += __shfl_xor(accy, 32, 64);
    dn   += __shfl_xor(dn,   16, 64); dn   += __shfl_xor(dn,   32, 64);
    float iv = 1.f / dn;
    int c0 = 2 * cp, c1 = c0 + 1;
    float v0 = accx * iv + b2[c0];
    v0 = (v0 - mu2[c0]) * (g2[c0] * rsqrtf(var2[c0] + BNEPS)) + be2[c0];
    v0 = (v0 > 0.f) ? v0 : (__expf(v0) - 1.f);
    float v1 = accy * iv + b2[c1];
    v1 = (v1 - mu2[c1]) * (g2[c1] * rsqrtf(var2[c1] + BNEPS)) + be2[c1];
    v1 = (v1 > 0.f) ? v1 : (__expf(v1) - 1.f);
#pragma unroll
    for (int rr = 0; rr < 3; ++rr) {
        int o = sub + rr * 4;
        float t = 0.f;
        if (o < 10) t = v0 * Wc[o * 32 + c0] + v1 * Wc[o * 32 + c1];
#pragma unroll
        for (int m = 8; m >= 1; m >>= 1) t += __shfl_xor(t, m, 64);
        if (cp == 0 && o < 10) out[(size_t)node * 10 + o] = t + bc[o];
    }
}

extern "C" void kernel_launch(void* const* d_in, const int* in_sizes, int n_in,
                              void* d_out, int out_size, void* d_ws, size_t ws_size,
                              hipStream_t stream)
{
    const float* x     = (const float*)d_in[0];
    const int*   ei    = (const int*)d_in[1];
    const float* W1    = (const float*)d_in[2];
    const float* asrc1 = (const float*)d_in[3];
    const float* adst1 = (const float*)d_in[4];
    const float* b1    = (const float*)d_in[5];
    const float* g1    = (const float*)d_in[6];
    const float* be1   = (const float*)d_in[7];
    const float* mu1   = (const float*)d_in[8];
    const float* var1  = (const float*)d_in[9];
    const float* W2    = (const float*)d_in[10];
    const float* asrc2 = (const float*)d_in[11];
    const float* adst2 = (const float*)d_in[12];
    const float* b2    = (const float*)d_in[13];
    const float* g2    = (const float*)d_in[14];
    const float* be2   = (const float*)d_in[15];
    const float* mu2   = (const float*)d_in[16];
    const float* var2  = (const float*)d_in[17];
    const float* Wc    = (const float*)d_in[18];
    const float* bc    = (const float*)d_in[19];

    int N_ = in_sizes[0] / 128;
    int E_ = in_sizes[1] / 2;
    int Etot = E_ + N_;
    const int* srcp = ei;
    const int* dstp = ei + E_;
    int chunk = (N_ + NPART - 1) / NPART;
    int pcap = Etot / NPART + 1024;

    char* ws = (char*)d_ws;
    size_t off = 0;
    auto alloc = [&](size_t bytes) -> char* {
        char* p = ws + off;
        off += (bytes + 255) & ~(size_t)255;
        return p;
    };
    __half2* h1h   = (__half2*)alloc((size_t)N_ * 64 * 4);
    float*   hbn1  = (float*)alloc((size_t)N_ * 128 * 4);
    __half2* h2h   = (__half2*)alloc((size_t)N_ * 16 * 4);
    float*   ssrc1 = (float*)alloc((size_t)N_ * 4 * 4);
    float*   sdst1 = (float*)alloc((size_t)N_ * 4 * 4);
    float*   ssrc2 = (float*)alloc((size_t)N_ * 4);
    float*   sdst2 = (float*)alloc((size_t)N_ * 4);
    int*     rowptr= (int*)alloc((size_t)(N_ + 1) * 4);
    int*     col   = (int*)alloc((size_t)Etot * 4);
    int2*    pairs = (int2*)alloc((size_t)NPART * pcap * 8);
    int*     pcur  = (int*)alloc((size_t)NPART * 4);

    hipMemsetAsync(pcur, 0, NPART * 4, stream);
    gemm1_kernel<<<(N_ + 63) / 64, 256, 0, stream>>>(x, W1, asrc1, adst1, h1h, ssrc1, sdst1, N_);
    int per_block = 256 * 8;
    part_kernel<<<(Etot + per_block - 1) / per_block, 256, 0, stream>>>(
        srcp, dstp, E_, Etot, chunk, pairs, pcap, pcur);
    csr_kernel<<<NPART, 256, 0, stream>>>(pairs, pcap, pcur, rowptr, col, N_, chunk, Etot);
    agg1_kernel<<<(N_ + 3) / 4, 256, 0, stream>>>(h1h, ssrc1, sdst1, rowptr, col,
                                                  b1, g1, be1, mu1, var1, hbn1, N_);
    gemm2_kernel<<<(N_ + 63) / 64, 256, 0, stream>>>(hbn1, W2, asrc2, adst2, h2h, ssrc2, sdst2, N_);
    agg2_kernel<<<(N_ + 3) / 4, 256, 0, stream>>>(h2h, ssrc2, sdst2, rowptr, col,
                                                  b2, g2, be2, mu2, var2, Wc, bc, (float*)d_out, N_);
}

// Round 7
// 161.657 us; speedup vs baseline: 3.3783x; 1.0334x over previous
//
#include <hip/hip_runtime.h>
#include <hip/hip_fp16.h>

#define NEG 0.2f
#define BNEPS 1e-5f
#define NPART 256

// ---------------- GEMM1: h1 = x @ W1^T  [N,128] (fp16 pairs) + s_src1/s_dst1 [N,4] ----------------
__global__ __launch_bounds__(256) void gemm1_kernel(
    const float* __restrict__ x, const float* __restrict__ W1,
    const float* __restrict__ asrc, const float* __restrict__ adst,
    __half2* __restrict__ h1h, float* __restrict__ ssrc1, float* __restrict__ sdst1, int n)
{
    __shared__ float At[32 * 68];    // [k][row]
    __shared__ float Bt[32 * 132];   // [k][col]
    int tid = threadIdx.x;
    int tx = tid & 15, ty = tid >> 4;
    int rbase = blockIdx.x * 64;

    int arow = tid >> 2, aq = tid & 3;
    int bc = tid >> 1, bq = tid & 1;
    int grow = rbase + arow;
    bool aval = grow < n;
    const float* xrow = x + (size_t)grow * 128;
    const float* wrow = W1 + (size_t)bc * 128;

    float acc_lo[4][4] = {{0.f}};
    float acc_hi[4][4] = {{0.f}};

    for (int kb = 0; kb < 128; kb += 32) {
        float4 av0, av1;
        if (aval) {
            av0 = *(const float4*)(xrow + kb + aq * 8);
            av1 = *(const float4*)(xrow + kb + aq * 8 + 4);
        } else {
            av0 = make_float4(0.f, 0.f, 0.f, 0.f); av1 = av0;
        }
        float4 bv0 = *(const float4*)(wrow + kb + bq * 16);
        float4 bv1 = *(const float4*)(wrow + kb + bq * 16 + 4);
        float4 bv2 = *(const float4*)(wrow + kb + bq * 16 + 8);
        float4 bv3 = *(const float4*)(wrow + kb + bq * 16 + 12);
        __syncthreads();
        {
            const float* a0 = (const float*)&av0;
            const float* a1 = (const float*)&av1;
#pragma unroll
            for (int j = 0; j < 4; ++j) At[(aq * 8 + j) * 68 + arow] = a0[j];
#pragma unroll
            for (int j = 0; j < 4; ++j) At[(aq * 8 + 4 + j) * 68 + arow] = a1[j];
            const float* bp0 = (const float*)&bv0;
            const float* bp1 = (const float*)&bv1;
            const float* bp2 = (const float*)&bv2;
            const float* bp3 = (const float*)&bv3;
#pragma unroll
            for (int j = 0; j < 4; ++j) Bt[(bq * 16 + j) * 132 + bc] = bp0[j];
#pragma unroll
            for (int j = 0; j < 4; ++j) Bt[(bq * 16 + 4 + j) * 132 + bc] = bp1[j];
#pragma unroll
            for (int j = 0; j < 4; ++j) Bt[(bq * 16 + 8 + j) * 132 + bc] = bp2[j];
#pragma unroll
            for (int j = 0; j < 4; ++j) Bt[(bq * 16 + 12 + j) * 132 + bc] = bp3[j];
        }
        __syncthreads();
#pragma unroll
        for (int k = 0; k < 32; ++k) {
            float4 af = *(const float4*)&At[k * 68 + ty * 4];
            float4 bl = *(const float4*)&Bt[k * 132 + tx * 4];
            float4 bh = *(const float4*)&Bt[k * 132 + 64 + tx * 4];
            const float* ap = (const float*)&af;
            const float* blp = (const float*)&bl;
            const float* bhp = (const float*)&bh;
#pragma unroll
            for (int r = 0; r < 4; ++r) {
#pragma unroll
                for (int j = 0; j < 4; ++j) {
                    acc_lo[r][j] += ap[r] * blp[j];
                    acc_hi[r][j] += ap[r] * bhp[j];
                }
            }
        }
    }

    float4 as_lo = *(const float4*)(asrc + 4 * tx);
    float4 as_hi = *(const float4*)(asrc + 64 + 4 * tx);
    float4 ad_lo = *(const float4*)(adst + 4 * tx);
    float4 ad_hi = *(const float4*)(adst + 64 + 4 * tx);
    const float* aslp = (const float*)&as_lo;
    const float* ashp = (const float*)&as_hi;
    const float* adlp = (const float*)&ad_lo;
    const float* adhp = (const float*)&ad_hi;

#pragma unroll
    for (int r = 0; r < 4; ++r) {
        int row = rbase + 4 * ty + r;
        if (row >= n) continue;
        __half2* hp = h1h + (size_t)row * 64;
        hp[2 * tx]     = __floats2half2_rn(acc_lo[r][0], acc_lo[r][1]);
        hp[2 * tx + 1] = __floats2half2_rn(acc_lo[r][2], acc_lo[r][3]);
        hp[32 + 2 * tx]     = __floats2half2_rn(acc_hi[r][0], acc_hi[r][1]);
        hp[32 + 2 * tx + 1] = __floats2half2_rn(acc_hi[r][2], acc_hi[r][3]);
        float sls = 0.f, sld = 0.f, shs = 0.f, shd = 0.f;
#pragma unroll
        for (int j = 0; j < 4; ++j) {
            sls += acc_lo[r][j] * aslp[j];
            sld += acc_lo[r][j] * adlp[j];
            shs += acc_hi[r][j] * ashp[j];
            shd += acc_hi[r][j] * adhp[j];
        }
#pragma unroll
        for (int m = 1; m <= 4; m <<= 1) {
            sls += __shfl_xor(sls, m, 64);
            sld += __shfl_xor(sld, m, 64);
            shs += __shfl_xor(shs, m, 64);
            shd += __shfl_xor(shd, m, 64);
        }
        if ((tx & 7) == 0) {
            int hl = tx >> 3;
            ssrc1[row * 4 + hl] = sls;
            sdst1[row * 4 + hl] = sld;
            ssrc1[row * 4 + 2 + hl] = shs;
            sdst1[row * 4 + 2 + hl] = shd;
        }
    }
}

// ---------------- CSR pass 1: partition edges into 256 dst-range buckets ----------------
__global__ __launch_bounds__(256) void part_kernel(
    const int* __restrict__ srcp, const int* __restrict__ dstp, int E, int Etot, int chunk,
    int2* __restrict__ pairs, int pcap, int* __restrict__ pcur)
{
    __shared__ int lcnt[NPART], lbase[NPART];
    const int PER = 8;
    int t0 = blockIdx.x * 256 * PER;
    int tid = threadIdx.x;
    lcnt[tid] = 0;
    __syncthreads();
    int myd[PER], mys[PER], myp[PER];
#pragma unroll
    for (int j = 0; j < PER; ++j) {
        int i = t0 + j * 256 + tid;
        if (i < Etot) {
            int s, d;
            if (i < E) { s = srcp[i]; d = dstp[i]; } else { s = i - E; d = i - E; }
            myd[j] = d; mys[j] = s; myp[j] = d / chunk;
            atomicAdd(&lcnt[myp[j]], 1);
        } else myp[j] = -1;
    }
    __syncthreads();
    lbase[tid] = atomicAdd(&pcur[tid], lcnt[tid]);
    lcnt[tid] = 0;
    __syncthreads();
#pragma unroll
    for (int j = 0; j < PER; ++j) {
        if (myp[j] >= 0) {
            int r = atomicAdd(&lcnt[myp[j]], 1);
            int pos = lbase[myp[j]] + r;
            if (pos < pcap) pairs[(size_t)myp[j] * pcap + pos] = make_int2(myd[j], mys[j]);
        }
    }
}

// ---------------- CSR pass 2: one block per partition — deg count, scan, scatter ----------------
__global__ __launch_bounds__(256) void csr_kernel(
    const int2* __restrict__ pairs, int pcap, const int* __restrict__ pcnt,
    int* __restrict__ rowptr, int* __restrict__ col, int N, int chunk, int Etot)
{
    __shared__ int ldeg[NPART];
    __shared__ int wtmp[4];
    __shared__ int sh_pbase;
    int p = blockIdx.x;
    int lo = p * chunk;
    int hi = min(lo + chunk, N);
    int len = max(hi - lo, 0);
    int tid = threadIdx.x;
    int lane = tid & 63, wv = tid >> 6;

    {
        int v = pcnt[tid];
        int inc = v;
#pragma unroll
        for (int m = 1; m < 64; m <<= 1) {
            int t = __shfl_up(inc, m, 64);
            if (lane >= m) inc += t;
        }
        if (lane == 63) wtmp[wv] = inc;
        __syncthreads();
        int woff = 0;
        for (int w = 0; w < wv; ++w) woff += wtmp[w];
        if (tid == p) sh_pbase = inc - v + woff;
        ldeg[tid] = 0;
        __syncthreads();
    }

    int cnt = min(pcnt[p], pcap);
    const int2* pp = pairs + (size_t)p * pcap;
    for (int i = tid; i < cnt; i += 256) {
        atomicAdd(&ldeg[pp[i].x - lo], 1);
    }
    __syncthreads();

    int v = (tid < len) ? ldeg[tid] : 0;
    int inc = v;
#pragma unroll
    for (int m = 1; m < 64; m <<= 1) {
        int t = __shfl_up(inc, m, 64);
        if (lane >= m) inc += t;
    }
    if (lane == 63) wtmp[wv] = inc;
    __syncthreads();
    int woff = 0;
    for (int w = 0; w < wv; ++w) woff += wtmp[w];
    int excl = inc - v + woff;
    int base = sh_pbase;
    __syncthreads();
    if (tid < len) {
        rowptr[lo + tid] = base + excl;
        ldeg[tid] = base + excl;
    }
    if (p == NPART - 1 && tid == 0) rowptr[N] = Etot;
    __syncthreads();

    for (int i = tid; i < cnt; i += 256) {
        int2 e = pp[i];
        int pos = atomicAdd(&ldeg[e.x - lo], 1);
        col[pos] = e.y;
    }
}

// ---------------- GAT layer-1: 4-edges-in-flight aggregate + bias + BN1 + ELU ----------------
// Wave = 4 groups x 16 lanes. Group g takes edges start+g, start+g+4, ...
// Lane (g, q) owns channels 8q..8q+7 (head q>>2): one float4 (16B) of the h1h row.
__global__ __launch_bounds__(256) void agg1_kernel(
    const __half2* __restrict__ h1h, const float* __restrict__ ssrc1, const float* __restrict__ sdst1,
    const int* __restrict__ rowptr, const int* __restrict__ col,
    const float* __restrict__ b1, const float* __restrict__ g1, const float* __restrict__ be1,
    const float* __restrict__ mu1, const float* __restrict__ var1,
    float* __restrict__ hbn1, int n)
{
    int node = blockIdx.x * 4 + (threadIdx.x >> 6);
    int lane = threadIdx.x & 63;
    if (node >= n) return;
    int start = rowptr[node], end = rowptr[node + 1];
    int g = lane >> 4;          // edge group
    int q = lane & 15;          // channel quad
    int hd = q >> 2;            // head of my 8 channels
    float sdh = sdst1[node * 4 + hd];

    float acc[8] = {0.f, 0.f, 0.f, 0.f, 0.f, 0.f, 0.f, 0.f};
    float dn = 0.f;
#pragma unroll 2
    for (int j = start + g; j < end; j += 4) {
        int s = col[j];
        float e = ssrc1[s * 4 + hd] + sdh;
        e = (e > 0.f) ? e : NEG * e;
        float w = __expf(e);
        dn += w;
        float4 hv = *(const float4*)((const char*)(h1h + (size_t)s * 64) + 16 * q);
        const __half2* hp = (const __half2*)&hv;
#pragma unroll
        for (int t = 0; t < 4; ++t) {
            float2 f = __half22float2(hp[t]);
            acc[2 * t]     += w * f.x;
            acc[2 * t + 1] += w * f.y;
        }
    }
    // combine the 4 groups (lane bits 4,5)
#pragma unroll
    for (int m = 16; m <= 32; m <<= 1) {
        dn += __shfl_xor(dn, m, 64);
#pragma unroll
        for (int t = 0; t < 8; ++t) acc[t] += __shfl_xor(acc[t], m, 64);
    }
    if (lane < 16) {
        float iv = 1.f / dn;
        int c = 8 * q;
        float4 b0 = *(const float4*)(b1 + c),   b4 = *(const float4*)(b1 + c + 4);
        float4 g0 = *(const float4*)(g1 + c),   g4 = *(const float4*)(g1 + c + 4);
        float4 e0 = *(const float4*)(be1 + c),  e4 = *(const float4*)(be1 + c + 4);
        float4 m0 = *(const float4*)(mu1 + c),  m4 = *(const float4*)(mu1 + c + 4);
        float4 v0 = *(const float4*)(var1 + c), v4 = *(const float4*)(var1 + c + 4);
        const float* bp = (const float*)&b0;  const float* bp4 = (const float*)&b4;
        const float* gp = (const float*)&g0;  const float* gp4 = (const float*)&g4;
        const float* ep = (const float*)&e0;  const float* ep4 = (const float*)&e4;
        const float* mp = (const float*)&m0;  const float* mp4 = (const float*)&m4;
        const float* vp = (const float*)&v0;  const float* vp4 = (const float*)&v4;
        float out[8];
#pragma unroll
        for (int t = 0; t < 4; ++t) {
            float u = acc[t] * iv + bp[t];
            u = (u - mp[t]) * (gp[t] * rsqrtf(vp[t] + BNEPS)) + ep[t];
            out[t] = (u > 0.f) ? u : (__expf(u) - 1.f);
        }
#pragma unroll
        for (int t = 0; t < 4; ++t) {
            float u = acc[4 + t] * iv + bp4[t];
            u = (u - mp4[t]) * (gp4[t] * rsqrtf(vp4[t] + BNEPS)) + ep4[t];
            out[4 + t] = (u > 0.f) ? u : (__expf(u) - 1.f);
        }
        float* op = hbn1 + (size_t)node * 128 + c;
        *(float4*)op       = make_float4(out[0], out[1], out[2], out[3]);
        *(float4*)(op + 4) = make_float4(out[4], out[5], out[6], out[7]);
    }
}

// ---------------- GEMM2: h2 = hbn1 @ W2^T  [N,32] (fp16 pairs) + s_src2/s_dst2 [N] ----------------
__global__ __launch_bounds__(256) void gemm2_kernel(
    const float* __restrict__ hbn1, const float* __restrict__ W2,
    const float* __restrict__ asrc2, const float* __restrict__ adst2,
    __half2* __restrict__ h2h, float* __restrict__ ssrc2, float* __restrict__ sdst2, int n)
{
    __shared__ float At[32 * 68];
    __shared__ float Bt[32 * 36];
    int tid = threadIdx.x;
    int tx = tid & 15, ty = tid >> 4;
    int rbase = blockIdx.x * 64;

    int arow = tid >> 2, aq = tid & 3;
    int bc = tid >> 3, bq = tid & 7;
    int grow = rbase + arow;
    bool aval = grow < n;
    const float* xrow = hbn1 + (size_t)grow * 128;
    const float* wrow = W2 + (size_t)bc * 128;

    float acc[4][2] = {{0.f}};

    for (int kb = 0; kb < 128; kb += 32) {
        float4 av0, av1;
        if (aval) {
            av0 = *(const float4*)(xrow + kb + aq * 8);
            av1 = *(const float4*)(xrow + kb + aq * 8 + 4);
        } else {
            av0 = make_float4(0.f, 0.f, 0.f, 0.f); av1 = av0;
        }
        float4 bv = *(const float4*)(wrow + kb + bq * 4);
        __syncthreads();
        {
            const float* a0 = (const float*)&av0;
            const float* a1 = (const float*)&av1;
#pragma unroll
            for (int j = 0; j < 4; ++j) At[(aq * 8 + j) * 68 + arow] = a0[j];
#pragma unroll
            for (int j = 0; j < 4; ++j) At[(aq * 8 + 4 + j) * 68 + arow] = a1[j];
            const float* bp = (const float*)&bv;
#pragma unroll
            for (int j = 0; j < 4; ++j) Bt[(bq * 4 + j) * 36 + bc] = bp[j];
        }
        __syncthreads();
#pragma unroll
        for (int k = 0; k < 32; ++k) {
            float4 af = *(const float4*)&At[k * 68 + ty * 4];
            float2 bf = *(const float2*)&Bt[k * 36 + 2 * tx];
            const float* ap = (const float*)&af;
#pragma unroll
            for (int r = 0; r < 4; ++r) {
                acc[r][0] += ap[r] * bf.x;
                acc[r][1] += ap[r] * bf.y;
            }
        }
    }

    float as0 = asrc2[2 * tx], as1 = asrc2[2 * tx + 1];
    float ad0 = adst2[2 * tx], ad1 = adst2[2 * tx + 1];
#pragma unroll
    for (int r = 0; r < 4; ++r) {
        int row = rbase + 4 * ty + r;
        if (row >= n) continue;
        h2h[(size_t)row * 16 + tx] = __floats2half2_rn(acc[r][0], acc[r][1]);
        float ts = acc[r][0] * as0 + acc[r][1] * as1;
        float td = acc[r][0] * ad0 + acc[r][1] * ad1;
#pragma unroll
        for (int m = 1; m <= 8; m <<= 1) {
            ts += __shfl_xor(ts, m, 64);
            td += __shfl_xor(td, m, 64);
        }
        if (tx == 0) { ssrc2[row] = ts; sdst2[row] = td; }
    }
}

// ---------------- GAT layer-2: single-pass aggregate + BN2 + ELU + classifier ----------------
__global__ __launch_bounds__(256) void agg2_kernel(
    const __half2* __restrict__ h2h, const float* __restrict__ ssrc2, const float* __restrict__ sdst2,
    const int* __restrict__ rowptr, const int* __restrict__ col,
    const float* __restrict__ b2, const float* __restrict__ g2, const float* __restrict__ be2,
    const float* __restrict__ mu2, const float* __restrict__ var2,
    const float* __restrict__ Wc, const float* __restrict__ bc,
    float* __restrict__ out, int n)
{
    int node = blockIdx.x * 4 + (threadIdx.x >> 6);
    int lane = threadIdx.x & 63;
    if (node >= n) return;
    int start = rowptr[node], end = rowptr[node + 1];
    int cp = lane & 15, sub = lane >> 4;
    float sd = sdst2[node];
    float accx = 0.f, accy = 0.f, dn = 0.f;
    for (int j = start + sub; j < end; j += 4) {
        int s = col[j];
        float e = ssrc2[s] + sd;
        e = (e > 0.f) ? e : NEG * e;
        float w = __expf(e);
        dn += w;
        float2 hf = __half22float2(h2h[(size_t)s * 16 + cp]);
        accx += w * hf.x;
        accy += w * hf.y;
    }
    accx += __shfl_xor(accx, 16, 64); accx += __shfl_xor(accx, 32, 64);
    accy += __shfl_xor(accy, 16, 64); accy += __shfl_xor(accy, 32, 64);
    dn   += __shfl_xor(dn,   16, 64); dn   += __shfl_xor(dn,   32, 64);
    float iv = 1.f / dn;
    int c0 = 2 * cp, c1 = c0 + 1;
    float v0 = accx * iv + b2[c0];
    v0 = (v0 - mu2[c0]) * (g2[c0] * rsqrtf(var2[c0] + BNEPS)) + be2[c0];
    v0 = (v0 > 0.f) ? v0 : (__expf(v0) - 1.f);
    float v1 = accy * iv + b2[c1];
    v1 = (v1 - mu2[c1]) * (g2[c1] * rsqrtf(var2[c1] + BNEPS)) + be2[c1];
    v1 = (v1 > 0.f) ? v1 : (__expf(v1) - 1.f);
#pragma unroll
    for (int rr = 0; rr < 3; ++rr) {
        int o = sub + rr * 4;
        float t = 0.f;
        if (o < 10) t = v0 * Wc[o * 32 + c0] + v1 * Wc[o * 32 + c1];
#pragma unroll
        for (int m = 8; m >= 1; m >>= 1) t += __shfl_xor(t, m, 64);
        if (cp == 0 && o < 10) out[(size_t)node * 10 + o] = t + bc[o];
    }
}

extern "C" void kernel_launch(void* const* d_in, const int* in_sizes, int n_in,
                              void* d_out, int out_size, void* d_ws, size_t ws_size,
                              hipStream_t stream)
{
    const float* x     = (const float*)d_in[0];
    const int*   ei    = (const int*)d_in[1];
    const float* W1    = (const float*)d_in[2];
    const float* asrc1 = (const float*)d_in[3];
    const float* adst1 = (const float*)d_in[4];
    const float* b1    = (const float*)d_in[5];
    const float* g1    = (const float*)d_in[6];
    const float* be1   = (const float*)d_in[7];
    const float* mu1   = (const float*)d_in[8];
    const float* var1  = (const float*)d_in[9];
    const float* W2    = (const float*)d_in[10];
    const float* asrc2 = (const float*)d_in[11];
    const float* adst2 = (const float*)d_in[12];
    const float* b2    = (const float*)d_in[13];
    const float* g2    = (const float*)d_in[14];
    const float* be2   = (const float*)d_in[15];
    const float* mu2   = (const float*)d_in[16];
    const float* var2  = (const float*)d_in[17];
    const float* Wc    = (const float*)d_in[18];
    const float* bc    = (const float*)d_in[19];

    int N_ = in_sizes[0] / 128;
    int E_ = in_sizes[1] / 2;
    int Etot = E_ + N_;
    const int* srcp = ei;
    const int* dstp = ei + E_;
    int chunk = (N_ + NPART - 1) / NPART;
    int pcap = Etot / NPART + 1024;

    char* ws = (char*)d_ws;
    size_t off = 0;
    auto alloc = [&](size_t bytes) -> char* {
        char* p = ws + off;
        off += (bytes + 255) & ~(size_t)255;
        return p;
    };
    __half2* h1h   = (__half2*)alloc((size_t)N_ * 64 * 4);
    float*   hbn1  = (float*)alloc((size_t)N_ * 128 * 4);
    __half2* h2h   = (__half2*)alloc((size_t)N_ * 16 * 4);
    float*   ssrc1 = (float*)alloc((size_t)N_ * 4 * 4);
    float*   sdst1 = (float*)alloc((size_t)N_ * 4 * 4);
    float*   ssrc2 = (float*)alloc((size_t)N_ * 4);
    float*   sdst2 = (float*)alloc((size_t)N_ * 4);
    int*     rowptr= (int*)alloc((size_t)(N_ + 1) * 4);
    int*     col   = (int*)alloc((size_t)Etot * 4);
    int2*    pairs = (int2*)alloc((size_t)NPART * pcap * 8);
    int*     pcur  = (int*)alloc((size_t)NPART * 4);

    hipMemsetAsync(pcur, 0, NPART * 4, stream);
    gemm1_kernel<<<(N_ + 63) / 64, 256, 0, stream>>>(x, W1, asrc1, adst1, h1h, ssrc1, sdst1, N_);
    int per_block = 256 * 8;
    part_kernel<<<(Etot + per_block - 1) / per_block, 256, 0, stream>>>(
        srcp, dstp, E_, Etot, chunk, pairs, pcap, pcur);
    csr_kernel<<<NPART, 256, 0, stream>>>(pairs, pcap, pcur, rowptr, col, N_, chunk, Etot);
    agg1_kernel<<<(N_ + 3) / 4, 256, 0, stream>>>(h1h, ssrc1, sdst1, rowptr, col,
                                                  b1, g1, be1, mu1, var1, hbn1, N_);
    gemm2_kernel<<<(N_ + 63) / 64, 256, 0, stream>>>(hbn1, W2, asrc2, adst2, h2h, ssrc2, sdst2, N_);
    agg2_kernel<<<(N_ + 3) / 4, 256, 0, stream>>>(h2h, ssrc2, sdst2, rowptr, col,
                                                  b2, g2, be2, mu2, var2, Wc, bc, (float*)d_out, N_);
}